// Round 1
// baseline (1012.492 us; speedup 1.0000x reference)
//
#include <hip/hip_runtime.h>
#include <cstdint>
#include <cstddef>

#define Nn   50000
#define Ee   800000
#define ETOT 850000   // edges + self loops
#define HID  128
#define Gg   16
#define NEG_SLOPE 0.2f
#define EPS_GN 1e-5f

static __device__ __forceinline__ float lrelu(float v) { return v > 0.f ? v : NEG_SLOPE * v; }

// ---------------------------------------------------------------------------
// CSR build
// ---------------------------------------------------------------------------
__global__ void count_deg(const int* __restrict__ edst, int* __restrict__ deg) {
    int i = blockIdx.x * 256 + threadIdx.x;
    if (i >= ETOT) return;
    int dst = (i < Ee) ? edst[i] : (i - Ee);
    atomicAdd(&deg[dst], 1);
}

__global__ __launch_bounds__(1024) void scan1(const int* __restrict__ deg,
                                              int* __restrict__ rowptr,
                                              int* __restrict__ bsums) {
    __shared__ int sm[1024];
    int tid = threadIdx.x;
    int i = blockIdx.x * 1024 + tid;
    sm[tid] = (i < Nn) ? deg[i] : 0;
    __syncthreads();
    for (int off = 1; off < 1024; off <<= 1) {
        int t = 0;
        if (tid >= off) t = sm[tid - off];
        __syncthreads();
        sm[tid] += t;
        __syncthreads();
    }
    if (i < Nn) rowptr[i + 1] = sm[tid];
    if (tid == 1023) bsums[blockIdx.x] = sm[1023];
}

__global__ void scan2(int* __restrict__ bsums, int nb) {
    if (threadIdx.x == 0 && blockIdx.x == 0) {
        int run = 0;
        for (int b = 0; b < nb; b++) { int t = bsums[b]; bsums[b] = run; run += t; }
    }
}

__global__ void scan3(int* __restrict__ rowptr, const int* __restrict__ bsums) {
    int i = blockIdx.x * 256 + threadIdx.x;
    if (i == 0) rowptr[0] = 0;
    if (i < Nn) rowptr[i + 1] += bsums[i >> 10];
}

__global__ void scatter_edges(const int* __restrict__ esrc, const int* __restrict__ edst,
                              int* __restrict__ cur, int* __restrict__ col) {
    int i = blockIdx.x * 256 + threadIdx.x;
    if (i >= ETOT) return;
    int src, dst;
    if (i < Ee) { src = esrc[i]; dst = edst[i]; }
    else        { src = i - Ee; dst = src; }
    int pos = atomicAdd(&cur[dst], 1);
    col[pos] = src;
}

// ---------------------------------------------------------------------------
// Register-tiled fp32 GEMM: C[M,128] = A[M,K] @ B[K,128] (+bias)
// Block tile 128x128, 256 threads, per-thread 8x8.
// ---------------------------------------------------------------------------
#define BKK 32
#define APAD 132   // words; %32==4 keeps transpose-write conflicts to 4-way

template <int K, bool BIAS>
__global__ __launch_bounds__(256) void gemm_nn(const float* __restrict__ Ag,
                                               const float* __restrict__ Bg,
                                               const float* __restrict__ bias,
                                               float* __restrict__ Cg, int M) {
    __shared__ float At[BKK * APAD];  // transposed: At[k*APAD + r]
    __shared__ float Bs[BKK * 128];
    int t  = threadIdx.x;
    int tx = t & 15, ty = t >> 4;
    int row0 = blockIdx.x * 128;
    float acc[8][8] = {};

    for (int k0 = 0; k0 < K; k0 += BKK) {
#pragma unroll
        for (int i = 0; i < 4; i++) {
            int f4 = t + 256 * i;      // 0..1023 float4 slots of the 128x32 A chunk
            int r  = f4 >> 3;
            int kq = f4 & 7;
            float4 v = make_float4(0.f, 0.f, 0.f, 0.f);
            int gr = row0 + r;
            if (gr < M) v = *(const float4*)(Ag + (size_t)gr * K + k0 + kq * 4);
            At[(kq * 4 + 0) * APAD + r] = v.x;
            At[(kq * 4 + 1) * APAD + r] = v.y;
            At[(kq * 4 + 2) * APAD + r] = v.z;
            At[(kq * 4 + 3) * APAD + r] = v.w;
        }
#pragma unroll
        for (int i = 0; i < 4; i++) {
            int f4 = t + 256 * i;      // 32x128 B chunk
            int k  = f4 >> 5;
            int c4 = (f4 & 31) * 4;
            *(float4*)(Bs + k * 128 + c4) = *(const float4*)(Bg + (size_t)(k0 + k) * 128 + c4);
        }
        __syncthreads();
#pragma unroll
        for (int k = 0; k < BKK; k++) {
            float4 a0 = *(const float4*)(At + k * APAD + 4 * ty);
            float4 a1 = *(const float4*)(At + k * APAD + 64 + 4 * ty);
            float4 b0 = *(const float4*)(Bs + k * 128 + 4 * tx);
            float4 b1 = *(const float4*)(Bs + k * 128 + 64 + 4 * tx);
            float a[8] = {a0.x, a0.y, a0.z, a0.w, a1.x, a1.y, a1.z, a1.w};
            float b[8] = {b0.x, b0.y, b0.z, b0.w, b1.x, b1.y, b1.z, b1.w};
#pragma unroll
            for (int i = 0; i < 8; i++)
#pragma unroll
                for (int j = 0; j < 8; j++) acc[i][j] += a[i] * b[j];
        }
        __syncthreads();
    }

#pragma unroll
    for (int i = 0; i < 8; i++) {
        int rl = (i < 4) ? (4 * ty + i) : (64 + 4 * ty + (i - 4));
        int r = row0 + rl;
        if (r >= M) continue;
#pragma unroll
        for (int jb = 0; jb < 2; jb++) {
            int c = jb * 64 + 4 * tx;
            float4 v = make_float4(acc[i][jb * 4 + 0], acc[i][jb * 4 + 1],
                                   acc[i][jb * 4 + 2], acc[i][jb * 4 + 3]);
            if (BIAS) {
                v.x += bias[c]; v.y += bias[c + 1]; v.z += bias[c + 2]; v.w += bias[c + 3];
            }
            *(float4*)(Cg + (size_t)r * 128 + c) = v;
        }
    }
}

// ---------------------------------------------------------------------------
// Per-(node,head) attention logits: es/ed [N,8]
// ---------------------------------------------------------------------------
__global__ __launch_bounds__(256) void att_scores(const float* __restrict__ hp,
                                                  const float* __restrict__ asrc,
                                                  const float* __restrict__ adst,
                                                  float* __restrict__ es,
                                                  float* __restrict__ ed) {
    int i = blockIdx.x * 256 + threadIdx.x;  // n*8 + head
    if (i >= Nn * 8) return;
    int hh = i & 7;
    const float* hrow = hp + (size_t)(i >> 3) * 128 + hh * 16;
    const float* av = asrc + hh * 16;
    const float* dv = adst + hh * 16;
    float s1 = 0.f, s2 = 0.f;
#pragma unroll
    for (int d = 0; d < 16; d++) {
        float x = hrow[d];
        s1 += x * av[d];
        s2 += x * dv[d];
    }
    es[i] = s1;
    ed[i] = s2;
}

// ---------------------------------------------------------------------------
// GAT aggregation: one wave per destination node.
// Phase A: softmax denominator per head (lanes over edges, shuffle reduce).
// Phase B: lanes = channels, serial over edges, accumulate alpha * hp[src].
// out = attn + gat_bias + residual(hin)
// ---------------------------------------------------------------------------
__global__ __launch_bounds__(256) void gat_attn(const float* __restrict__ hp,
                                                const float* __restrict__ hin,
                                                const float* __restrict__ es,
                                                const float* __restrict__ ed,
                                                const int* __restrict__ rowptr,
                                                const int* __restrict__ col,
                                                const float* __restrict__ gbias,
                                                float* __restrict__ out) {
    __shared__ float sinv[4][8];
    int w    = threadIdx.x >> 6;
    int lane = threadIdx.x & 63;
    int n    = blockIdx.x * 4 + w;   // grid sized exactly: Nn/4 blocks
    int start = rowptr[n], end = rowptr[n + 1];

    float edv[8];
    {
        float4 a = *(const float4*)(ed + (size_t)n * 8);
        float4 b = *(const float4*)(ed + (size_t)n * 8 + 4);
        edv[0] = a.x; edv[1] = a.y; edv[2] = a.z; edv[3] = a.w;
        edv[4] = b.x; edv[5] = b.y; edv[6] = b.z; edv[7] = b.w;
    }

    // ---- phase A: denominators ----
    float sacc[8] = {0.f, 0.f, 0.f, 0.f, 0.f, 0.f, 0.f, 0.f};
    for (int e = start + lane; e < end; e += 64) {
        int src = col[e];
        float4 a = *(const float4*)(es + (size_t)src * 8);
        float4 b = *(const float4*)(es + (size_t)src * 8 + 4);
        float ev[8] = {a.x, a.y, a.z, a.w, b.x, b.y, b.z, b.w};
#pragma unroll
        for (int i = 0; i < 8; i++) sacc[i] += __expf(lrelu(ev[i] + edv[i]));
    }
#pragma unroll
    for (int i = 0; i < 8; i++) {
#pragma unroll
        for (int off = 32; off > 0; off >>= 1) sacc[i] += __shfl_xor(sacc[i], off);
    }
    if (lane == 0) {
#pragma unroll
        for (int i = 0; i < 8; i++) sinv[w][i] = 1.0f / (sacc[i] + 1e-16f);
    }
    // wave-local LDS write->read; program order within a wave suffices

    // ---- phase B: accumulate ----
    int h0 = lane >> 4;                 // head for channel c=lane (0..3)
    float inv0 = sinv[w][h0];
    float inv1 = sinv[w][h0 + 4];
    float ed0 = ed[(size_t)n * 8 + h0];
    float ed1 = ed[(size_t)n * 8 + h0 + 4];
    float acc0 = 0.f, acc1 = 0.f;
    for (int e = start; e < end; e++) {
        int src = col[e];
        float x0 = es[(size_t)src * 8 + h0];
        float x1 = es[(size_t)src * 8 + h0 + 4];
        float a0 = __expf(lrelu(x0 + ed0)) * inv0;
        float a1 = __expf(lrelu(x1 + ed1)) * inv1;
        acc0 += a0 * hp[(size_t)src * 128 + lane];
        acc1 += a1 * hp[(size_t)src * 128 + 64 + lane];
    }
    size_t idx = (size_t)n * 128 + lane;
    out[idx]      = acc0 + gbias[lane]      + hin[idx];
    out[idx + 64] = acc1 + gbias[lane + 64] + hin[idx + 64];
}

// ---------------------------------------------------------------------------
// GraphNorm stats: per (g,c) sum and sumsq; batch is sorted so use run flush.
// ---------------------------------------------------------------------------
#define SCHUNK 64
__global__ __launch_bounds__(128) void gn_stats(const float* __restrict__ x,
                                                const int* __restrict__ batch,
                                                float* __restrict__ sumx,
                                                float* __restrict__ sumxx,
                                                float* __restrict__ cnt) {
    int c  = threadIdx.x;
    int n0 = blockIdx.x * SCHUNK;
    int n1 = n0 + SCHUNK;
    if (n1 > Nn) n1 = Nn;
    if (n0 >= Nn) return;
    int curG = batch[n0];
    float sx = 0.f, sxx = 0.f;
    int run = 0;
    for (int n = n0; n < n1; n++) {
        int g = batch[n];
        if (g != curG) {
            atomicAdd(&sumx[curG * 128 + c], sx);
            atomicAdd(&sumxx[curG * 128 + c], sxx);
            if (c == 0) atomicAdd(&cnt[curG], (float)run);
            sx = 0.f; sxx = 0.f; run = 0; curG = g;
        }
        float v = x[(size_t)n * 128 + c];
        sx += v; sxx += v * v; run++;
    }
    atomicAdd(&sumx[curG * 128 + c], sx);
    atomicAdd(&sumxx[curG * 128 + c], sxx);
    if (c == 0) atomicAdd(&cnt[curG], (float)run);
}

__global__ void gn_final(const float* __restrict__ sumx, const float* __restrict__ sumxx,
                         const float* __restrict__ cnt, const float* __restrict__ w,
                         const float* __restrict__ b, const float* __restrict__ s,
                         float* __restrict__ Ab, float* __restrict__ Bb) {
    int i = blockIdx.x * blockDim.x + threadIdx.x;
    if (i >= Gg * 128) return;
    int g = i >> 7, c = i & 127;
    float cn  = cnt[g];
    float m   = sumx[i] / cn;
    float msq = sumxx[i] / cn;
    float sc  = s[c];
    // E[(x - sc*m)^2] = E[x^2] - (2*sc - sc^2) * m^2  (exact rewrite of reference)
    float varo = msq - (2.f * sc - sc * sc) * m * m;
    float inv  = rsqrtf(varo + EPS_GN);
    float Ai   = inv * w[c];
    Ab[i] = Ai;
    Bb[i] = b[c] - sc * m * Ai;
    (void)g;
}

__global__ __launch_bounds__(256) void gn_apply(const float* __restrict__ x,
                                                const int* __restrict__ batch,
                                                const float* __restrict__ Ab,
                                                const float* __restrict__ Bb,
                                                float* __restrict__ out) {
    int idx = blockIdx.x * 256 + threadIdx.x;  // float4 granularity: N*32 total
    int n = idx >> 5;
    if (n >= Nn) return;
    int c4 = (idx & 31) << 2;
    int g = batch[n];
    float4 xv = *(const float4*)(x + (size_t)n * 128 + c4);
    float4 Av = *(const float4*)(Ab + g * 128 + c4);
    float4 Bv = *(const float4*)(Bb + g * 128 + c4);
    float4 o;
    o.x = xv.x * Av.x + Bv.x;
    o.y = xv.y * Av.y + Bv.y;
    o.z = xv.z * Av.z + Bv.z;
    o.w = xv.w * Av.w + Bv.w;
    *(float4*)(out + (size_t)n * 128 + c4) = o;
}

// ---------------------------------------------------------------------------
// Launch
// ---------------------------------------------------------------------------
extern "C" void kernel_launch(void* const* d_in, const int* in_sizes, int n_in,
                              void* d_out, int out_size, void* d_ws, size_t ws_size,
                              hipStream_t stream) {
    const float* x      = (const float*)d_in[0];
    const int*   eidx   = (const int*)d_in[1];     // [2,E]
    const int*   batch  = (const int*)d_in[2];
    const float* in_W   = (const float*)d_in[3];
    const float* in_b   = (const float*)d_in[4];
    const float* Wg     = (const float*)d_in[5];   // [4,128,128]
    const float* attS   = (const float*)d_in[6];   // [4,8,16]
    const float* attD   = (const float*)d_in[7];
    const float* gat_b  = (const float*)d_in[8];   // [4,128]
    const float* gn_w   = (const float*)d_in[9];
    const float* gn_b   = (const float*)d_in[10];
    const float* gn_s   = (const float*)d_in[11];

    const int* esrc = eidx;
    const int* edst = eidx + Ee;

    // workspace carve (256B aligned)
    char* p = (char*)d_ws;
    auto carve = [&](size_t bytes) {
        void* r = (void*)p;
        p += (bytes + 255) & ~(size_t)255;
        return r;
    };
    float* h    = (float*)carve((size_t)Nn * 128 * 4);
    float* hp   = (float*)carve((size_t)Nn * 128 * 4);
    float* h2   = (float*)carve((size_t)Nn * 128 * 4);
    float* es   = (float*)carve((size_t)Nn * 8 * 4);
    float* ed   = (float*)carve((size_t)Nn * 8 * 4);
    float* sumx = (float*)carve((size_t)(Gg * 128 * 2 + 16) * 4);  // sumx|sumxx|cnt contiguous
    float* sumxx = sumx + Gg * 128;
    float* cntf  = sumx + Gg * 128 * 2;
    float* Abuf = (float*)carve((size_t)Gg * 128 * 4);
    float* Bbuf = (float*)carve((size_t)Gg * 128 * 4);
    int* rowptr = (int*)carve((size_t)(Nn + 1) * 4);
    int* deg    = (int*)carve((size_t)Nn * 4);
    int* cur    = (int*)carve((size_t)Nn * 4);
    int* col    = (int*)carve((size_t)ETOT * 4);
    int* bsums  = (int*)carve(64 * 4);

    // ---- CSR build (once per call) ----
    hipMemsetAsync(deg, 0, (size_t)Nn * 4, stream);
    count_deg<<<(ETOT + 255) / 256, 256, 0, stream>>>(edst, deg);
    scan1<<<(Nn + 1023) / 1024, 1024, 0, stream>>>(deg, rowptr, bsums);
    scan2<<<1, 64, 0, stream>>>(bsums, (Nn + 1023) / 1024);
    scan3<<<(Nn + 255) / 256, 256, 0, stream>>>(rowptr, bsums);
    hipMemcpyAsync(cur, rowptr, (size_t)Nn * 4, hipMemcpyDeviceToDevice, stream);
    scatter_edges<<<(ETOT + 255) / 256, 256, 0, stream>>>(esrc, edst, cur, col);

    const int gemm_grid = (Nn + 127) / 128;  // 391

    // ---- input projection ----
    gemm_nn<64, true><<<gemm_grid, 256, 0, stream>>>(x, in_W, in_b, h, Nn);

    // ---- layers ----
    for (int l = 0; l < 4; l++) {
        gemm_nn<128, false><<<gemm_grid, 256, 0, stream>>>(h, Wg + (size_t)l * 128 * 128,
                                                           nullptr, hp, Nn);
        att_scores<<<(Nn * 8 + 255) / 256, 256, 0, stream>>>(hp, attS + l * 128,
                                                             attD + l * 128, es, ed);
        gat_attn<<<Nn / 4, 256, 0, stream>>>(hp, h, es, ed, rowptr, col,
                                             gat_b + l * 128, h2);
        hipMemsetAsync(sumx, 0, (size_t)(Gg * 128 * 2 + 16) * 4, stream);
        gn_stats<<<(Nn + SCHUNK - 1) / SCHUNK, 128, 0, stream>>>(h2, batch, sumx, sumxx, cntf);
        gn_final<<<8, 256, 0, stream>>>(sumx, sumxx, cntf, gn_w + l * 128,
                                        gn_b + l * 128, gn_s + l * 128, Abuf, Bbuf);
        float* outp = (l == 3) ? (float*)d_out : h;
        gn_apply<<<(Nn * 32 + 255) / 256, 256, 0, stream>>>(h2, batch, Abuf, Bbuf, outp);
    }
    (void)in_sizes; (void)n_in; (void)out_size; (void)ws_size;
}

// Round 2
// 849.783 us; speedup vs baseline: 1.1915x; 1.1915x over previous
//
#include <hip/hip_runtime.h>
#include <cstdint>
#include <cstddef>

#define Nn   50000
#define Ee   800000
#define ETOT 850000   // edges + self loops
#define HID  128
#define Gg   16
#define NEG_SLOPE 0.2f
#define EPS_GN 1e-5f

static __device__ __forceinline__ float lrelu(float v) { return v > 0.f ? v : NEG_SLOPE * v; }

// ---------------------------------------------------------------------------
// CSR build
// ---------------------------------------------------------------------------
__global__ void count_deg(const int* __restrict__ edst, int* __restrict__ deg) {
    int i = blockIdx.x * 256 + threadIdx.x;
    if (i >= ETOT) return;
    int dst = (i < Ee) ? edst[i] : (i - Ee);
    atomicAdd(&deg[dst], 1);
}

__global__ __launch_bounds__(1024) void scan1(const int* __restrict__ deg,
                                              int* __restrict__ rowptr,
                                              int* __restrict__ bsums) {
    __shared__ int sm[1024];
    int tid = threadIdx.x;
    int i = blockIdx.x * 1024 + tid;
    sm[tid] = (i < Nn) ? deg[i] : 0;
    __syncthreads();
    for (int off = 1; off < 1024; off <<= 1) {
        int t = 0;
        if (tid >= off) t = sm[tid - off];
        __syncthreads();
        sm[tid] += t;
        __syncthreads();
    }
    if (i < Nn) rowptr[i + 1] = sm[tid];
    if (tid == 1023) bsums[blockIdx.x] = sm[1023];
}

__global__ void scan2(int* __restrict__ bsums, int nb) {
    if (threadIdx.x == 0 && blockIdx.x == 0) {
        int run = 0;
        for (int b = 0; b < nb; b++) { int t = bsums[b]; bsums[b] = run; run += t; }
    }
}

__global__ void scan3(int* __restrict__ rowptr, const int* __restrict__ bsums) {
    int i = blockIdx.x * 256 + threadIdx.x;
    if (i == 0) rowptr[0] = 0;
    if (i < Nn) rowptr[i + 1] += bsums[i >> 10];
}

__global__ void scatter_edges(const int* __restrict__ esrc, const int* __restrict__ edst,
                              int* __restrict__ cur, int* __restrict__ col) {
    int i = blockIdx.x * 256 + threadIdx.x;
    if (i >= ETOT) return;
    int src, dst;
    if (i < Ee) { src = esrc[i]; dst = edst[i]; }
    else        { src = i - Ee; dst = src; }
    int pos = atomicAdd(&cur[dst], 1);
    col[pos] = src;
}

// ---------------------------------------------------------------------------
// Register-tiled fp32 GEMM: C[M,128] = A[M,K] @ B[K,128] (+bias)
// Block tile 128x128, 256 threads, per-thread 8x8.
// ---------------------------------------------------------------------------
#define BKK 32
#define APAD 132   // words; %32==4 keeps transpose-write conflicts to 4-way

template <int K, bool BIAS>
__global__ __launch_bounds__(256) void gemm_nn(const float* __restrict__ Ag,
                                               const float* __restrict__ Bg,
                                               const float* __restrict__ bias,
                                               float* __restrict__ Cg, int M) {
    __shared__ float At[BKK * APAD];  // transposed: At[k*APAD + r]
    __shared__ float Bs[BKK * 128];
    int t  = threadIdx.x;
    int tx = t & 15, ty = t >> 4;
    int row0 = blockIdx.x * 128;
    float acc[8][8] = {};

    for (int k0 = 0; k0 < K; k0 += BKK) {
#pragma unroll
        for (int i = 0; i < 4; i++) {
            int f4 = t + 256 * i;      // 0..1023 float4 slots of the 128x32 A chunk
            int r  = f4 >> 3;
            int kq = f4 & 7;
            float4 v = make_float4(0.f, 0.f, 0.f, 0.f);
            int gr = row0 + r;
            if (gr < M) v = *(const float4*)(Ag + (size_t)gr * K + k0 + kq * 4);
            At[(kq * 4 + 0) * APAD + r] = v.x;
            At[(kq * 4 + 1) * APAD + r] = v.y;
            At[(kq * 4 + 2) * APAD + r] = v.z;
            At[(kq * 4 + 3) * APAD + r] = v.w;
        }
#pragma unroll
        for (int i = 0; i < 4; i++) {
            int f4 = t + 256 * i;      // 32x128 B chunk
            int k  = f4 >> 5;
            int c4 = (f4 & 31) * 4;
            *(float4*)(Bs + k * 128 + c4) = *(const float4*)(Bg + (size_t)(k0 + k) * 128 + c4);
        }
        __syncthreads();
#pragma unroll
        for (int k = 0; k < BKK; k++) {
            float4 a0 = *(const float4*)(At + k * APAD + 4 * ty);
            float4 a1 = *(const float4*)(At + k * APAD + 64 + 4 * ty);
            float4 b0 = *(const float4*)(Bs + k * 128 + 4 * tx);
            float4 b1 = *(const float4*)(Bs + k * 128 + 64 + 4 * tx);
            float a[8] = {a0.x, a0.y, a0.z, a0.w, a1.x, a1.y, a1.z, a1.w};
            float b[8] = {b0.x, b0.y, b0.z, b0.w, b1.x, b1.y, b1.z, b1.w};
#pragma unroll
            for (int i = 0; i < 8; i++)
#pragma unroll
                for (int j = 0; j < 8; j++) acc[i][j] += a[i] * b[j];
        }
        __syncthreads();
    }

#pragma unroll
    for (int i = 0; i < 8; i++) {
        int rl = (i < 4) ? (4 * ty + i) : (64 + 4 * ty + (i - 4));
        int r = row0 + rl;
        if (r >= M) continue;
#pragma unroll
        for (int jb = 0; jb < 2; jb++) {
            int c = jb * 64 + 4 * tx;
            float4 v = make_float4(acc[i][jb * 4 + 0], acc[i][jb * 4 + 1],
                                   acc[i][jb * 4 + 2], acc[i][jb * 4 + 3]);
            if (BIAS) {
                v.x += bias[c]; v.y += bias[c + 1]; v.z += bias[c + 2]; v.w += bias[c + 3];
            }
            *(float4*)(Cg + (size_t)r * 128 + c) = v;
        }
    }
}

// ---------------------------------------------------------------------------
// Per-(node,head) attention logits: es/ed [N,8]
// ---------------------------------------------------------------------------
__global__ __launch_bounds__(256) void att_scores(const float* __restrict__ hp,
                                                  const float* __restrict__ asrc,
                                                  const float* __restrict__ adst,
                                                  float* __restrict__ es,
                                                  float* __restrict__ ed) {
    int i = blockIdx.x * 256 + threadIdx.x;  // n*8 + head
    if (i >= Nn * 8) return;
    int hh = i & 7;
    const float4* hrow = (const float4*)(hp + (size_t)(i >> 3) * 128 + hh * 16);
    const float4* av   = (const float4*)(asrc + hh * 16);
    const float4* dv   = (const float4*)(adst + hh * 16);
    float s1 = 0.f, s2 = 0.f;
#pragma unroll
    for (int q = 0; q < 4; q++) {
        float4 x = hrow[q], a = av[q], d = dv[q];
        s1 += x.x * a.x + x.y * a.y + x.z * a.z + x.w * a.w;
        s2 += x.x * d.x + x.y * d.y + x.z * d.z + x.w * d.w;
    }
    es[i] = s1;
    ed[i] = s2;
}

// ---------------------------------------------------------------------------
// GAT aggregation, single-pass: one wave per destination node.
// Edges in groups of 8: lane l computes weight for edge-slot l>>3, head l&7
// (one exp chain per 8 edges). Inner unrolled loop broadcasts (src, w) via
// shuffles; each lane accumulates channels {2l, 2l+1} (same head = l>>3).
// Softmax denominator = xor-shuffle reduction of the per-lane weight sums;
// normalize at the end:  out = (sum_e w_e * h[src]) / (sum_e w_e).
// ---------------------------------------------------------------------------
__global__ __launch_bounds__(256) void gat_attn(const float* __restrict__ hp,
                                                const float* __restrict__ hin,
                                                const float* __restrict__ es,
                                                const float* __restrict__ ed,
                                                const int* __restrict__ rowptr,
                                                const int* __restrict__ col,
                                                const float* __restrict__ gbias,
                                                float* __restrict__ out) {
    int w    = threadIdx.x >> 6;
    int lane = threadIdx.x & 63;
    int n    = blockIdx.x * 4 + w;   // grid sized exactly: Nn/4 blocks
    int start = rowptr[n], end = rowptr[n + 1];

    int slot = lane >> 3;   // edge slot within a group of 8
    int ah   = lane & 7;    // head this lane computes weights for
    int ch   = lane >> 3;   // head of channel pair {2*lane, 2*lane+1}

    float edh = ed[(size_t)n * 8 + ah];

    float2 acc = make_float2(0.f, 0.f);
    float dacc = 0.f;

    int e0 = start;
    // full groups of 8
    for (; e0 + 8 <= end; e0 += 8) {
        int src_l = col[e0 + slot];
        float wgt = __expf(lrelu(es[(size_t)src_l * 8 + ah] + edh));
        dacc += wgt;
#pragma unroll
        for (int j = 0; j < 8; j++) {
            int   src_j = __shfl(src_l, j * 8);
            float wj    = __shfl(wgt,   j * 8 + ch);
            float2 hv = *(const float2*)(hp + (size_t)src_j * 128 + 2 * lane);
            acc.x += wj * hv.x;
            acc.y += wj * hv.y;
        }
    }
    // remainder group
    if (e0 < end) {
        int rem = end - e0;                      // 1..7, wave-uniform
        int eb  = e0 + slot;
        int ec  = (slot < rem) ? eb : (end - 1); // clamp (row非empty: self-loop)
        int src_l = col[ec];
        float wgt = (slot < rem) ? __expf(lrelu(es[(size_t)src_l * 8 + ah] + edh)) : 0.f;
        dacc += wgt;
        for (int j = 0; j < rem; j++) {          // uniform trip count
            int   src_j = __shfl(src_l, j * 8);
            float wj    = __shfl(wgt,   j * 8 + ch);
            float2 hv = *(const float2*)(hp + (size_t)src_j * 128 + 2 * lane);
            acc.x += wj * hv.x;
            acc.y += wj * hv.y;
        }
    }

    // denominator: reduce over the 8 edge-slots (lanes sharing `ah`)
    dacc += __shfl_xor(dacc, 8);
    dacc += __shfl_xor(dacc, 16);
    dacc += __shfl_xor(dacc, 32);
    float inv  = 1.0f / (dacc + 1e-16f);   // every lane: inv for its own ah
    float winv = __shfl(inv, ch);          // lane `ch` holds inv for head `ch`

    size_t idx = (size_t)n * 128 + 2 * lane;
    float2 res = *(const float2*)(hin + idx);
    float2 o;
    o.x = acc.x * winv + gbias[2 * lane]     + res.x;
    o.y = acc.y * winv + gbias[2 * lane + 1] + res.y;
    *(float2*)(out + idx) = o;
}

// ---------------------------------------------------------------------------
// GraphNorm stats: per (g,c) sum and sumsq; batch is sorted so use run flush.
// ---------------------------------------------------------------------------
#define SCHUNK 64
__global__ __launch_bounds__(128) void gn_stats(const float* __restrict__ x,
                                                const int* __restrict__ batch,
                                                float* __restrict__ sumx,
                                                float* __restrict__ sumxx,
                                                float* __restrict__ cnt) {
    int c  = threadIdx.x;
    int n0 = blockIdx.x * SCHUNK;
    int n1 = n0 + SCHUNK;
    if (n1 > Nn) n1 = Nn;
    if (n0 >= Nn) return;
    int curG = batch[n0];
    float sx = 0.f, sxx = 0.f;
    int run = 0;
    for (int n = n0; n < n1; n++) {
        int g = batch[n];
        if (g != curG) {
            atomicAdd(&sumx[curG * 128 + c], sx);
            atomicAdd(&sumxx[curG * 128 + c], sxx);
            if (c == 0) atomicAdd(&cnt[curG], (float)run);
            sx = 0.f; sxx = 0.f; run = 0; curG = g;
        }
        float v = x[(size_t)n * 128 + c];
        sx += v; sxx += v * v; run++;
    }
    atomicAdd(&sumx[curG * 128 + c], sx);
    atomicAdd(&sumxx[curG * 128 + c], sxx);
    if (c == 0) atomicAdd(&cnt[curG], (float)run);
}

__global__ void gn_final(const float* __restrict__ sumx, const float* __restrict__ sumxx,
                         const float* __restrict__ cnt, const float* __restrict__ w,
                         const float* __restrict__ b, const float* __restrict__ s,
                         float* __restrict__ Ab, float* __restrict__ Bb) {
    int i = blockIdx.x * blockDim.x + threadIdx.x;
    if (i >= Gg * 128) return;
    int g = i >> 7, c = i & 127;
    float cn  = cnt[g];
    float m   = sumx[i] / cn;
    float msq = sumxx[i] / cn;
    float sc  = s[c];
    // E[(x - sc*m)^2] = E[x^2] - (2*sc - sc^2) * m^2  (exact rewrite of reference)
    float varo = msq - (2.f * sc - sc * sc) * m * m;
    float inv  = rsqrtf(varo + EPS_GN);
    float Ai   = inv * w[c];
    Ab[i] = Ai;
    Bb[i] = b[c] - sc * m * Ai;
    (void)g;
}

__global__ __launch_bounds__(256) void gn_apply(const float* __restrict__ x,
                                                const int* __restrict__ batch,
                                                const float* __restrict__ Ab,
                                                const float* __restrict__ Bb,
                                                float* __restrict__ out) {
    int idx = blockIdx.x * 256 + threadIdx.x;  // float4 granularity: N*32 total
    int n = idx >> 5;
    if (n >= Nn) return;
    int c4 = (idx & 31) << 2;
    int g = batch[n];
    float4 xv = *(const float4*)(x + (size_t)n * 128 + c4);
    float4 Av = *(const float4*)(Ab + g * 128 + c4);
    float4 Bv = *(const float4*)(Bb + g * 128 + c4);
    float4 o;
    o.x = xv.x * Av.x + Bv.x;
    o.y = xv.y * Av.y + Bv.y;
    o.z = xv.z * Av.z + Bv.z;
    o.w = xv.w * Av.w + Bv.w;
    *(float4*)(out + (size_t)n * 128 + c4) = o;
}

// ---------------------------------------------------------------------------
// Launch
// ---------------------------------------------------------------------------
extern "C" void kernel_launch(void* const* d_in, const int* in_sizes, int n_in,
                              void* d_out, int out_size, void* d_ws, size_t ws_size,
                              hipStream_t stream) {
    const float* x      = (const float*)d_in[0];
    const int*   eidx   = (const int*)d_in[1];     // [2,E]
    const int*   batch  = (const int*)d_in[2];
    const float* in_W   = (const float*)d_in[3];
    const float* in_b   = (const float*)d_in[4];
    const float* Wg     = (const float*)d_in[5];   // [4,128,128]
    const float* attS   = (const float*)d_in[6];   // [4,8,16]
    const float* attD   = (const float*)d_in[7];
    const float* gat_b  = (const float*)d_in[8];   // [4,128]
    const float* gn_w   = (const float*)d_in[9];
    const float* gn_b   = (const float*)d_in[10];
    const float* gn_s   = (const float*)d_in[11];

    const int* esrc = eidx;
    const int* edst = eidx + Ee;

    // workspace carve (256B aligned)
    char* p = (char*)d_ws;
    auto carve = [&](size_t bytes) {
        void* r = (void*)p;
        p += (bytes + 255) & ~(size_t)255;
        return r;
    };
    float* h    = (float*)carve((size_t)Nn * 128 * 4);
    float* hp   = (float*)carve((size_t)Nn * 128 * 4);
    float* h2   = (float*)carve((size_t)Nn * 128 * 4);
    float* es   = (float*)carve((size_t)Nn * 8 * 4);
    float* ed   = (float*)carve((size_t)Nn * 8 * 4);
    float* sumx = (float*)carve((size_t)(Gg * 128 * 2 + 16) * 4);  // sumx|sumxx|cnt contiguous
    float* sumxx = sumx + Gg * 128;
    float* cntf  = sumx + Gg * 128 * 2;
    float* Abuf = (float*)carve((size_t)Gg * 128 * 4);
    float* Bbuf = (float*)carve((size_t)Gg * 128 * 4);
    int* rowptr = (int*)carve((size_t)(Nn + 1) * 4);
    int* deg    = (int*)carve((size_t)Nn * 4);
    int* cur    = (int*)carve((size_t)Nn * 4);
    int* col    = (int*)carve((size_t)ETOT * 4);
    int* bsums  = (int*)carve(64 * 4);

    // ---- CSR build (once per call) ----
    hipMemsetAsync(deg, 0, (size_t)Nn * 4, stream);
    count_deg<<<(ETOT + 255) / 256, 256, 0, stream>>>(edst, deg);
    scan1<<<(Nn + 1023) / 1024, 1024, 0, stream>>>(deg, rowptr, bsums);
    scan2<<<1, 64, 0, stream>>>(bsums, (Nn + 1023) / 1024);
    scan3<<<(Nn + 255) / 256, 256, 0, stream>>>(rowptr, bsums);
    hipMemcpyAsync(cur, rowptr, (size_t)Nn * 4, hipMemcpyDeviceToDevice, stream);
    scatter_edges<<<(ETOT + 255) / 256, 256, 0, stream>>>(esrc, edst, cur, col);

    const int gemm_grid = (Nn + 127) / 128;  // 391

    // ---- input projection ----
    gemm_nn<64, true><<<gemm_grid, 256, 0, stream>>>(x, in_W, in_b, h, Nn);

    // ---- layers ----
    for (int l = 0; l < 4; l++) {
        gemm_nn<128, false><<<gemm_grid, 256, 0, stream>>>(h, Wg + (size_t)l * 128 * 128,
                                                           nullptr, hp, Nn);
        att_scores<<<(Nn * 8 + 255) / 256, 256, 0, stream>>>(hp, attS + l * 128,
                                                             attD + l * 128, es, ed);
        gat_attn<<<Nn / 4, 256, 0, stream>>>(hp, h, es, ed, rowptr, col,
                                             gat_b + l * 128, h2);
        hipMemsetAsync(sumx, 0, (size_t)(Gg * 128 * 2 + 16) * 4, stream);
        gn_stats<<<(Nn + SCHUNK - 1) / SCHUNK, 128, 0, stream>>>(h2, batch, sumx, sumxx, cntf);
        gn_final<<<8, 256, 0, stream>>>(sumx, sumxx, cntf, gn_w + l * 128,
                                        gn_b + l * 128, gn_s + l * 128, Abuf, Bbuf);
        float* outp = (l == 3) ? (float*)d_out : h;
        gn_apply<<<(Nn * 32 + 255) / 256, 256, 0, stream>>>(h2, batch, Abuf, Bbuf, outp);
    }
    (void)in_sizes; (void)n_in; (void)out_size; (void)ws_size;
}

// Round 3
// 673.574 us; speedup vs baseline: 1.5032x; 1.2616x over previous
//
#include <hip/hip_runtime.h>
#include <cstdint>
#include <cstddef>

#define Nn   50000
#define Ee   800000
#define ETOT 850000   // edges + self loops
#define HID  128
#define Gg   16
#define NEG_SLOPE 0.2f
#define EPS_GN 1e-5f

static __device__ __forceinline__ float lrelu(float v) { return v > 0.f ? v : NEG_SLOPE * v; }

// round-to-nearest-even fp32 -> bf16 (as ushort in low 16 bits of uint)
static __device__ __forceinline__ unsigned int f2bf(float x) {
    unsigned int u = __float_as_uint(x);
    return (u + 0x7fffu + ((u >> 16) & 1u)) >> 16;
}
static __device__ __forceinline__ float bf_lo(unsigned int u) {  // low bf16 -> float
    return __uint_as_float(u << 16);
}
static __device__ __forceinline__ float bf_hi(unsigned int u) {  // high bf16 -> float
    return __uint_as_float(u & 0xffff0000u);
}

// ---------------------------------------------------------------------------
// CSR build
// ---------------------------------------------------------------------------
__global__ void count_deg(const int* __restrict__ edst, int* __restrict__ deg) {
    int i = blockIdx.x * 256 + threadIdx.x;
    if (i >= ETOT) return;
    int dst = (i < Ee) ? edst[i] : (i - Ee);
    atomicAdd(&deg[dst], 1);
}

__global__ __launch_bounds__(1024) void scan1(const int* __restrict__ deg,
                                              int* __restrict__ rowptr,
                                              int* __restrict__ bsums) {
    __shared__ int sm[1024];
    int tid = threadIdx.x;
    int i = blockIdx.x * 1024 + tid;
    sm[tid] = (i < Nn) ? deg[i] : 0;
    __syncthreads();
    for (int off = 1; off < 1024; off <<= 1) {
        int t = 0;
        if (tid >= off) t = sm[tid - off];
        __syncthreads();
        sm[tid] += t;
        __syncthreads();
    }
    if (i < Nn) rowptr[i + 1] = sm[tid];
    if (tid == 1023) bsums[blockIdx.x] = sm[1023];
}

__global__ void scan2(int* __restrict__ bsums, int nb) {
    if (threadIdx.x == 0 && blockIdx.x == 0) {
        int run = 0;
        for (int b = 0; b < nb; b++) { int t = bsums[b]; bsums[b] = run; run += t; }
    }
}

__global__ void scan3(int* __restrict__ rowptr, const int* __restrict__ bsums) {
    int i = blockIdx.x * 256 + threadIdx.x;
    if (i == 0) rowptr[0] = 0;
    if (i < Nn) rowptr[i + 1] += bsums[i >> 10];
}

__global__ void scatter_edges(const int* __restrict__ esrc, const int* __restrict__ edst,
                              int* __restrict__ cur, int* __restrict__ col) {
    int i = blockIdx.x * 256 + threadIdx.x;
    if (i >= ETOT) return;
    int src, dst;
    if (i < Ee) { src = esrc[i]; dst = edst[i]; }
    else        { src = i - Ee; dst = src; }
    int pos = atomicAdd(&cur[dst], 1);
    col[pos] = src;
}

// ---------------------------------------------------------------------------
// Register-tiled fp32 GEMM: C[M,128] = affine?(A)[M,K] @ B[K,128] (+bias)
// Block tile 128x128, 256 threads, per-thread 8x8.
// AFFINE: A element (r,c) -> A*Ab[batch[r]*128+c] + Bb[...] (fused GraphNorm)
// OUT_BF16: write C as packed bf16 (RNE) instead of fp32.
// ---------------------------------------------------------------------------
#define BKK 32
#define APAD 132   // words; %32==4 keeps transpose-write conflicts to 4-way

template <int K, bool BIAS, bool AFFINE, bool OUT_BF16>
__global__ __launch_bounds__(256) void gemm_nn(const float* __restrict__ Ag,
                                               const int* __restrict__ batch,
                                               const float* __restrict__ Ab,
                                               const float* __restrict__ Bb,
                                               const float* __restrict__ Bg,
                                               const float* __restrict__ bias,
                                               float* __restrict__ Cf,
                                               unsigned int* __restrict__ Cb,  // bf16x2 packed
                                               int M) {
    __shared__ float At[BKK * APAD];  // transposed: At[k*APAD + r]
    __shared__ float Bs[BKK * 128];
    int t  = threadIdx.x;
    int tx = t & 15, ty = t >> 4;
    int row0 = blockIdx.x * 128;
    float acc[8][8] = {};

    for (int k0 = 0; k0 < K; k0 += BKK) {
#pragma unroll
        for (int i = 0; i < 4; i++) {
            int f4 = t + 256 * i;      // 0..1023 float4 slots of the 128x32 A chunk
            int r  = f4 >> 3;
            int kq = f4 & 7;
            float4 v = make_float4(0.f, 0.f, 0.f, 0.f);
            int gr = row0 + r;
            if (gr < M) {
                v = *(const float4*)(Ag + (size_t)gr * K + k0 + kq * 4);
                if (AFFINE) {
                    int g = batch[gr];
                    float4 Av = *(const float4*)(Ab + g * 128 + k0 + kq * 4);
                    float4 Bv = *(const float4*)(Bb + g * 128 + k0 + kq * 4);
                    v.x = v.x * Av.x + Bv.x;
                    v.y = v.y * Av.y + Bv.y;
                    v.z = v.z * Av.z + Bv.z;
                    v.w = v.w * Av.w + Bv.w;
                }
            }
            At[(kq * 4 + 0) * APAD + r] = v.x;
            At[(kq * 4 + 1) * APAD + r] = v.y;
            At[(kq * 4 + 2) * APAD + r] = v.z;
            At[(kq * 4 + 3) * APAD + r] = v.w;
        }
#pragma unroll
        for (int i = 0; i < 4; i++) {
            int f4 = t + 256 * i;      // 32x128 B chunk
            int k  = f4 >> 5;
            int c4 = (f4 & 31) * 4;
            *(float4*)(Bs + k * 128 + c4) = *(const float4*)(Bg + (size_t)(k0 + k) * 128 + c4);
        }
        __syncthreads();
#pragma unroll
        for (int k = 0; k < BKK; k++) {
            float4 a0 = *(const float4*)(At + k * APAD + 4 * ty);
            float4 a1 = *(const float4*)(At + k * APAD + 64 + 4 * ty);
            float4 b0 = *(const float4*)(Bs + k * 128 + 4 * tx);
            float4 b1 = *(const float4*)(Bs + k * 128 + 64 + 4 * tx);
            float a[8] = {a0.x, a0.y, a0.z, a0.w, a1.x, a1.y, a1.z, a1.w};
            float b[8] = {b0.x, b0.y, b0.z, b0.w, b1.x, b1.y, b1.z, b1.w};
#pragma unroll
            for (int i = 0; i < 8; i++)
#pragma unroll
                for (int j = 0; j < 8; j++) acc[i][j] += a[i] * b[j];
        }
        __syncthreads();
    }

#pragma unroll
    for (int i = 0; i < 8; i++) {
        int rl = (i < 4) ? (4 * ty + i) : (64 + 4 * ty + (i - 4));
        int r = row0 + rl;
        if (r >= M) continue;
#pragma unroll
        for (int jb = 0; jb < 2; jb++) {
            int c = jb * 64 + 4 * tx;
            float4 v = make_float4(acc[i][jb * 4 + 0], acc[i][jb * 4 + 1],
                                   acc[i][jb * 4 + 2], acc[i][jb * 4 + 3]);
            if (BIAS) {
                v.x += bias[c]; v.y += bias[c + 1]; v.z += bias[c + 2]; v.w += bias[c + 3];
            }
            if (OUT_BF16) {
                uint2 o;
                o.x = f2bf(v.x) | (f2bf(v.y) << 16);
                o.y = f2bf(v.z) | (f2bf(v.w) << 16);
                *(uint2*)(Cb + (size_t)r * 64 + (c >> 1)) = o;  // row = 64 uints
            } else {
                *(float4*)(Cf + (size_t)r * 128 + c) = v;
            }
        }
    }
}

// ---------------------------------------------------------------------------
// Per-(node,head) attention logits from bf16 hp: es/ed [N,8]
// ---------------------------------------------------------------------------
__global__ __launch_bounds__(256) void att_scores(const unsigned int* __restrict__ hp,
                                                  const float* __restrict__ asrc,
                                                  const float* __restrict__ adst,
                                                  float* __restrict__ es,
                                                  float* __restrict__ ed) {
    int i = blockIdx.x * 256 + threadIdx.x;  // n*8 + head
    if (i >= Nn * 8) return;
    int hh = i & 7;
    // head hh = channels [hh*16, hh*16+16) = uints [hh*8, hh*8+8)
    const uint4* p = (const uint4*)(hp + (size_t)(i >> 3) * 64 + hh * 8);
    uint4 q0 = p[0], q1 = p[1];
    unsigned int qq[8] = {q0.x, q0.y, q0.z, q0.w, q1.x, q1.y, q1.z, q1.w};
    const float* av = asrc + hh * 16;
    const float* dv = adst + hh * 16;
    float s1 = 0.f, s2 = 0.f;
#pragma unroll
    for (int q = 0; q < 8; q++) {
        float x0 = bf_lo(qq[q]), x1 = bf_hi(qq[q]);
        s1 += x0 * av[2 * q] + x1 * av[2 * q + 1];
        s2 += x0 * dv[2 * q] + x1 * dv[2 * q + 1];
    }
    es[i] = s1;
    ed[i] = s2;
}

// ---------------------------------------------------------------------------
// GAT aggregation, single-pass: one wave per destination node, bf16 gather.
// Edges in groups of 8: lane l computes weight for edge-slot l>>3, head l&7.
// Inner loop broadcasts (src, w) via shuffles; each lane accumulates channel
// pair {2l,2l+1} (one dword bf16x2 per edge). Denominator by shuffle reduce.
// Residual: hin fp32, optionally with fused GraphNorm affine (layers >=1).
// out = (sum w*h[src])/(sum w) + gbias + residual  (in-place safe: hin==out)
// ---------------------------------------------------------------------------
template <bool AFF>
__global__ __launch_bounds__(256) void gat_attn(const unsigned int* __restrict__ hp,
                                                const float* hin,
                                                const int* __restrict__ batch,
                                                const float* __restrict__ Ab,
                                                const float* __restrict__ Bb,
                                                const float* __restrict__ es,
                                                const float* __restrict__ ed,
                                                const int* __restrict__ rowptr,
                                                const int* __restrict__ col,
                                                const float* __restrict__ gbias,
                                                float* out) {
    int w    = threadIdx.x >> 6;
    int lane = threadIdx.x & 63;
    int n    = blockIdx.x * 4 + w;   // grid sized exactly: Nn/4 blocks
    int start = rowptr[n], end = rowptr[n + 1];

    int slot = lane >> 3;   // edge slot within a group of 8
    int ah   = lane & 7;    // head this lane computes weights for
    int ch   = lane >> 3;   // head of channel pair {2*lane, 2*lane+1}

    float edh = ed[(size_t)n * 8 + ah];

    float2 acc = make_float2(0.f, 0.f);
    float dacc = 0.f;

    int e0 = start;
    for (; e0 + 8 <= end; e0 += 8) {
        int src_l = col[e0 + slot];
        float wgt = __expf(lrelu(es[(size_t)src_l * 8 + ah] + edh));
        dacc += wgt;
#pragma unroll
        for (int j = 0; j < 8; j++) {
            int   src_j = __shfl(src_l, j * 8);
            float wj    = __shfl(wgt,   j * 8 + ch);
            unsigned int hv = hp[(size_t)src_j * 64 + lane];
            acc.x += wj * bf_lo(hv);
            acc.y += wj * bf_hi(hv);
        }
    }
    if (e0 < end) {
        int rem = end - e0;                      // 1..7, wave-uniform
        int eb  = e0 + slot;
        int ec  = (slot < rem) ? eb : (end - 1); // clamp (rows non-empty: self-loop)
        int src_l = col[ec];
        float wgt = (slot < rem) ? __expf(lrelu(es[(size_t)src_l * 8 + ah] + edh)) : 0.f;
        dacc += wgt;
        for (int j = 0; j < rem; j++) {          // uniform trip count
            int   src_j = __shfl(src_l, j * 8);
            float wj    = __shfl(wgt,   j * 8 + ch);
            unsigned int hv = hp[(size_t)src_j * 64 + lane];
            acc.x += wj * bf_lo(hv);
            acc.y += wj * bf_hi(hv);
        }
    }

    // denominator: reduce over the 8 edge-slots (lanes sharing `ah`)
    dacc += __shfl_xor(dacc, 8);
    dacc += __shfl_xor(dacc, 16);
    dacc += __shfl_xor(dacc, 32);
    float inv  = 1.0f / (dacc + 1e-16f);
    float winv = __shfl(inv, ch);          // inv for this lane's channel head

    size_t idx = (size_t)n * 128 + 2 * lane;
    float2 xv = *(const float2*)(hin + idx);
    float2 res;
    if (AFF) {
        int g = batch[n];
        float2 Av = *(const float2*)(Ab + g * 128 + 2 * lane);
        float2 Bv = *(const float2*)(Bb + g * 128 + 2 * lane);
        res.x = xv.x * Av.x + Bv.x;
        res.y = xv.y * Av.y + Bv.y;
    } else {
        res = xv;
    }
    float2 o;
    o.x = acc.x * winv + gbias[2 * lane]     + res.x;
    o.y = acc.y * winv + gbias[2 * lane + 1] + res.y;
    *(float2*)(out + idx) = o;
}

// ---------------------------------------------------------------------------
// GraphNorm stats: per (g,c) sum and sumsq; batch is sorted so use run flush.
// ---------------------------------------------------------------------------
#define SCHUNK 64
__global__ __launch_bounds__(128) void gn_stats(const float* __restrict__ x,
                                                const int* __restrict__ batch,
                                                float* __restrict__ sumx,
                                                float* __restrict__ sumxx,
                                                float* __restrict__ cnt) {
    int c  = threadIdx.x;
    int n0 = blockIdx.x * SCHUNK;
    int n1 = n0 + SCHUNK;
    if (n1 > Nn) n1 = Nn;
    if (n0 >= Nn) return;
    int curG = batch[n0];
    float sx = 0.f, sxx = 0.f;
    int run = 0;
    for (int n = n0; n < n1; n++) {
        int g = batch[n];
        if (g != curG) {
            atomicAdd(&sumx[curG * 128 + c], sx);
            atomicAdd(&sumxx[curG * 128 + c], sxx);
            if (c == 0) atomicAdd(&cnt[curG], (float)run);
            sx = 0.f; sxx = 0.f; run = 0; curG = g;
        }
        float v = x[(size_t)n * 128 + c];
        sx += v; sxx += v * v; run++;
    }
    atomicAdd(&sumx[curG * 128 + c], sx);
    atomicAdd(&sumxx[curG * 128 + c], sxx);
    if (c == 0) atomicAdd(&cnt[curG], (float)run);
}

__global__ void gn_final(const float* __restrict__ sumx, const float* __restrict__ sumxx,
                         const float* __restrict__ cnt, const float* __restrict__ w,
                         const float* __restrict__ b, const float* __restrict__ s,
                         float* __restrict__ Ab, float* __restrict__ Bb) {
    int i = blockIdx.x * blockDim.x + threadIdx.x;
    if (i >= Gg * 128) return;
    int g = i >> 7, c = i & 127;
    float cn  = cnt[g];
    float m   = sumx[i] / cn;
    float msq = sumxx[i] / cn;
    float sc  = s[c];
    // E[(x - sc*m)^2] = E[x^2] - (2*sc - sc^2) * m^2  (exact rewrite of reference)
    float varo = msq - (2.f * sc - sc * sc) * m * m;
    float inv  = rsqrtf(varo + EPS_GN);
    float Ai   = inv * w[c];
    Ab[i] = Ai;
    Bb[i] = b[c] - sc * m * Ai;
    (void)g;
}

__global__ __launch_bounds__(256) void gn_apply(const float* __restrict__ x,
                                                const int* __restrict__ batch,
                                                const float* __restrict__ Ab,
                                                const float* __restrict__ Bb,
                                                float* __restrict__ out) {
    int idx = blockIdx.x * 256 + threadIdx.x;  // float4 granularity: N*32 total
    int n = idx >> 5;
    if (n >= Nn) return;
    int c4 = (idx & 31) << 2;
    int g = batch[n];
    float4 xv = *(const float4*)(x + (size_t)n * 128 + c4);
    float4 Av = *(const float4*)(Ab + g * 128 + c4);
    float4 Bv = *(const float4*)(Bb + g * 128 + c4);
    float4 o;
    o.x = xv.x * Av.x + Bv.x;
    o.y = xv.y * Av.y + Bv.y;
    o.z = xv.z * Av.z + Bv.z;
    o.w = xv.w * Av.w + Bv.w;
    *(float4*)(out + (size_t)n * 128 + c4) = o;
}

// ---------------------------------------------------------------------------
// Launch
// ---------------------------------------------------------------------------
extern "C" void kernel_launch(void* const* d_in, const int* in_sizes, int n_in,
                              void* d_out, int out_size, void* d_ws, size_t ws_size,
                              hipStream_t stream) {
    const float* x      = (const float*)d_in[0];
    const int*   eidx   = (const int*)d_in[1];     // [2,E]
    const int*   batch  = (const int*)d_in[2];
    const float* in_W   = (const float*)d_in[3];
    const float* in_b   = (const float*)d_in[4];
    const float* Wg     = (const float*)d_in[5];   // [4,128,128]
    const float* attS   = (const float*)d_in[6];   // [4,8,16]
    const float* attD   = (const float*)d_in[7];
    const float* gat_b  = (const float*)d_in[8];   // [4,128]
    const float* gn_w   = (const float*)d_in[9];
    const float* gn_b   = (const float*)d_in[10];
    const float* gn_s   = (const float*)d_in[11];

    const int* esrc = eidx;
    const int* edst = eidx + Ee;

    // workspace carve (256B aligned)
    char* p = (char*)d_ws;
    auto carve = [&](size_t bytes) {
        void* r = (void*)p;
        p += (bytes + 255) & ~(size_t)255;
        return r;
    };
    float* h0   = (float*)carve((size_t)Nn * 128 * 4);       // input proj (fp32)
    unsigned int* hp = (unsigned int*)carve((size_t)Nn * 64 * 4);  // bf16x2 packed [N,64]
    float* h2   = (float*)carve((size_t)Nn * 128 * 4);       // pre-norm layer output
    float* es   = (float*)carve((size_t)Nn * 8 * 4);
    float* ed   = (float*)carve((size_t)Nn * 8 * 4);
    float* sumx = (float*)carve((size_t)(Gg * 128 * 2 + 16) * 4);
    float* sumxx = sumx + Gg * 128;
    float* cntf  = sumx + Gg * 128 * 2;
    float* Abuf = (float*)carve((size_t)Gg * 128 * 4);
    float* Bbuf = (float*)carve((size_t)Gg * 128 * 4);
    int* rowptr = (int*)carve((size_t)(Nn + 1) * 4);
    int* deg    = (int*)carve((size_t)Nn * 4);
    int* cur    = (int*)carve((size_t)Nn * 4);
    int* col    = (int*)carve((size_t)ETOT * 4);
    int* bsums  = (int*)carve(64 * 4);

    // ---- CSR build (once per call) ----
    hipMemsetAsync(deg, 0, (size_t)Nn * 4, stream);
    count_deg<<<(ETOT + 255) / 256, 256, 0, stream>>>(edst, deg);
    scan1<<<(Nn + 1023) / 1024, 1024, 0, stream>>>(deg, rowptr, bsums);
    scan2<<<1, 64, 0, stream>>>(bsums, (Nn + 1023) / 1024);
    scan3<<<(Nn + 255) / 256, 256, 0, stream>>>(rowptr, bsums);
    hipMemcpyAsync(cur, rowptr, (size_t)Nn * 4, hipMemcpyDeviceToDevice, stream);
    scatter_edges<<<(ETOT + 255) / 256, 256, 0, stream>>>(esrc, edst, cur, col);

    const int gemm_grid = (Nn + 127) / 128;  // 391

    // ---- input projection (fp32 out, no affine) ----
    gemm_nn<64, true, false, false><<<gemm_grid, 256, 0, stream>>>(
        x, nullptr, nullptr, nullptr, in_W, in_b, h0, nullptr, Nn);

    // ---- layers ----
    for (int l = 0; l < 4; l++) {
        // hp = affine?(h) @ Wg[l], bf16 out. Layer 0 reads h0 raw; layers 1-3
        // read h2 with fused GraphNorm affine of the previous layer.
        if (l == 0) {
            gemm_nn<128, false, false, true><<<gemm_grid, 256, 0, stream>>>(
                h0, nullptr, nullptr, nullptr, Wg + (size_t)l * 128 * 128,
                nullptr, nullptr, hp, Nn);
        } else {
            gemm_nn<128, false, true, true><<<gemm_grid, 256, 0, stream>>>(
                h2, batch, Abuf, Bbuf, Wg + (size_t)l * 128 * 128,
                nullptr, nullptr, hp, Nn);
        }
        att_scores<<<(Nn * 8 + 255) / 256, 256, 0, stream>>>(hp, attS + l * 128,
                                                             attD + l * 128, es, ed);
        if (l == 0) {
            gat_attn<false><<<Nn / 4, 256, 0, stream>>>(hp, h0, nullptr, nullptr, nullptr,
                                                        es, ed, rowptr, col,
                                                        gat_b + l * 128, h2);
        } else {
            gat_attn<true><<<Nn / 4, 256, 0, stream>>>(hp, h2, batch, Abuf, Bbuf,
                                                       es, ed, rowptr, col,
                                                       gat_b + l * 128, h2);
        }
        hipMemsetAsync(sumx, 0, (size_t)(Gg * 128 * 2 + 16) * 4, stream);
        gn_stats<<<(Nn + SCHUNK - 1) / SCHUNK, 128, 0, stream>>>(h2, batch, sumx, sumxx, cntf);
        gn_final<<<8, 256, 0, stream>>>(sumx, sumxx, cntf, gn_w + l * 128,
                                        gn_b + l * 128, gn_s + l * 128, Abuf, Bbuf);
    }
    // final normalize -> d_out
    gn_apply<<<(Nn * 32 + 255) / 256, 256, 0, stream>>>(h2, batch, Abuf, Bbuf,
                                                        (float*)d_out);
    (void)in_sizes; (void)n_in; (void)out_size; (void)ws_size;
}

// Round 4
// 598.327 us; speedup vs baseline: 1.6922x; 1.1258x over previous
//
#include <hip/hip_runtime.h>
#include <cstdint>
#include <cstddef>

#define Nn   50000
#define Ee   800000
#define ETOT 850000   // edges + self loops
#define HID  128
#define Gg   16
#define RSZ  6250     // Nn/8 : dst-range size per XCD team
#define NEG_SLOPE 0.2f
#define EPS_GN 1e-5f

typedef __attribute__((ext_vector_type(8))) short short8;
typedef __attribute__((ext_vector_type(4))) float f32x4;

static __device__ __forceinline__ float lrelu(float v) { return v > 0.f ? v : NEG_SLOPE * v; }

// round-to-nearest-even fp32 -> bf16 (low 16 bits of uint)
static __device__ __forceinline__ unsigned int f2bf(float x) {
    unsigned int u = __float_as_uint(x);
    return (u + 0x7fffu + ((u >> 16) & 1u)) >> 16;
}
static __device__ __forceinline__ float bf_lo(unsigned int u) { return __uint_as_float(u << 16); }
static __device__ __forceinline__ float bf_hi(unsigned int u) { return __uint_as_float(u & 0xffff0000u); }

// ---------------------------------------------------------------------------
// Weight prep: bf16 transpose of in_W [64][128]->Wt0[128][64] and
// Wg[4][128][128]->Wtl[4][128][128] ([n][k] layout)
// ---------------------------------------------------------------------------
__global__ void prep_w(const float* __restrict__ in_W, const float* __restrict__ Wg,
                       short* __restrict__ Wt0, short* __restrict__ Wtl) {
    int i = blockIdx.x * 256 + threadIdx.x;
    if (i < 8192) {                       // in-proj: n = i>>6, k = i&63
        int n = i >> 6, k = i & 63;
        Wt0[i] = (short)f2bf(in_W[k * 128 + n]);
    } else if (i < 73728) {
        int j = i - 8192;                 // j = l*16384 + n*128 + k
        int l = j >> 14;
        int rkn = j & 16383;
        int n = rkn >> 7, k = rkn & 127;
        Wtl[j] = (short)f2bf(Wg[l * 16384 + k * 128 + n]);
    }
}

// ---------------------------------------------------------------------------
// CSR build — XCD-partitioned: block b serves dst range (b&7); each team of
// (gridDim/8) blocks scans all edges, filters by range. All writes to
// deg/cur/col lines stay XCD-local -> no cross-XCD partial-line writebacks.
// ---------------------------------------------------------------------------
__global__ void count_deg(const int* __restrict__ edst, int* __restrict__ deg) {
    int r  = blockIdx.x & 7;
    int cb = blockIdx.x >> 3;
    int nb = gridDim.x >> 3;
    int lo = r * RSZ, hi = lo + RSZ;
    for (int i = cb * 256 + threadIdx.x; i < ETOT; i += nb * 256) {
        int dst = (i < Ee) ? edst[i] : (i - Ee);
        if (dst >= lo && dst < hi) atomicAdd(&deg[dst], 1);
    }
}

__global__ void scatter_edges(const int* __restrict__ esrc, const int* __restrict__ edst,
                              int* __restrict__ cur, int* __restrict__ col) {
    int r  = blockIdx.x & 7;
    int cb = blockIdx.x >> 3;
    int nb = gridDim.x >> 3;
    int lo = r * RSZ, hi = lo + RSZ;
    for (int i = cb * 256 + threadIdx.x; i < ETOT; i += nb * 256) {
        int dst = (i < Ee) ? edst[i] : (i - Ee);
        if (dst >= lo && dst < hi) {
            int src = (i < Ee) ? esrc[i] : dst;
            int pos = atomicAdd(&cur[dst], 1);
            col[pos] = src;
        }
    }
}

__global__ __launch_bounds__(1024) void scan1(const int* __restrict__ deg,
                                              int* __restrict__ rowptr,
                                              int* __restrict__ bsums) {
    __shared__ int sm[1024];
    int tid = threadIdx.x;
    int i = blockIdx.x * 1024 + tid;
    sm[tid] = (i < Nn) ? deg[i] : 0;
    __syncthreads();
    for (int off = 1; off < 1024; off <<= 1) {
        int t = 0;
        if (tid >= off) t = sm[tid - off];
        __syncthreads();
        sm[tid] += t;
        __syncthreads();
    }
    if (i < Nn) rowptr[i + 1] = sm[tid];
    if (tid == 1023) bsums[blockIdx.x] = sm[1023];
}

__global__ void scan2(int* __restrict__ bsums, int nb) {
    if (threadIdx.x == 0 && blockIdx.x == 0) {
        int run = 0;
        for (int b = 0; b < nb; b++) { int t = bsums[b]; bsums[b] = run; run += t; }
    }
}

__global__ void scan3(int* __restrict__ rowptr, const int* __restrict__ bsums) {
    int i = blockIdx.x * 256 + threadIdx.x;
    if (i == 0) rowptr[0] = 0;
    if (i < Nn) rowptr[i + 1] += bsums[i >> 10];
}

// ---------------------------------------------------------------------------
// MFMA bf16 GEMM: C[M,128] = affine?(A fp32 -> bf16)[M,K] @ W[K,128]
// Block 128x128, 4 waves (2x2 of 64x64), 16x16x32 bf16 MFMA.
// A: fp32 global -> bf16 LDS, padded stride K+8 shorts (16B-aligned b128,
//    uniform bank coverage). W: pre-transposed bf16 [n][k] global (L1-hot),
//    loaded as fragments. OUT_BF16: two-pass LDS repack (overlaying A buffer)
//    -> packed bf16x2. Else fp32 stores (+bias).
// ---------------------------------------------------------------------------
template <int K, bool AFFINE, bool OUT_BF16, bool BIAS>
__global__ __launch_bounds__(256) void gemm_mfma(const float* __restrict__ Ag,
                                                 const int* __restrict__ batch,
                                                 const float* __restrict__ Ab,
                                                 const float* __restrict__ Bb,
                                                 const short* __restrict__ Wt,
                                                 const float* __restrict__ bias,
                                                 float* __restrict__ Cf,
                                                 unsigned int* __restrict__ Cb,
                                                 int M) {
    constexpr int KP = K + 8;                    // padded shorts per A row
    constexpr int ABYTES = 128 * KP * 2;
    constexpr int CBYTES = OUT_BF16 ? 64 * 130 * 4 : 0;
    constexpr int SBYTES = ABYTES > CBYTES ? ABYTES : CBYTES;
    __shared__ __align__(16) char smem[SBYTES];
    short* As = (short*)smem;
    float* Cs = (float*)smem;   // overlays As (used only after all MFMA reads)

    int t    = threadIdx.x;
    int lane = t & 63;
    int w    = t >> 6;
    int wm   = (w & 1) * 64;
    int wn   = (w >> 1) * 64;
    int row0 = blockIdx.x * 128;

    // ---- stage A: fp32 -> bf16 LDS ----
    constexpr int F4R = K / 4;                   // float4 per row
    constexpr int ITERS = 128 * F4R / 256;
#pragma unroll
    for (int i = 0; i < ITERS; i++) {
        int f4 = t + 256 * i;
        int r  = f4 / F4R;
        int c4 = f4 % F4R;
        float4 v = make_float4(0.f, 0.f, 0.f, 0.f);
        int gr = row0 + r;
        if (gr < M) {
            v = *(const float4*)(Ag + (size_t)gr * K + c4 * 4);
            if (AFFINE) {
                int g = batch[gr];
                float4 Av = *(const float4*)(Ab + g * 128 + c4 * 4);
                float4 Bv = *(const float4*)(Bb + g * 128 + c4 * 4);
                v.x = v.x * Av.x + Bv.x;
                v.y = v.y * Av.y + Bv.y;
                v.z = v.z * Av.z + Bv.z;
                v.w = v.w * Av.w + Bv.w;
            }
        }
        uint2 pk;
        pk.x = f2bf(v.x) | (f2bf(v.y) << 16);
        pk.y = f2bf(v.z) | (f2bf(v.w) << 16);
        *(uint2*)(As + r * KP + c4 * 4) = pk;
    }
    __syncthreads();

    // ---- MFMA main loop ----
    f32x4 acc[4][4] = {};
    int am = wm + (lane & 15);
    int aq = (lane >> 4) * 8;
    const short* wb = Wt + (size_t)(wn + (lane & 15)) * K + aq;
#pragma unroll
    for (int kk = 0; kk < K / 32; kk++) {
        short8 a[4], b[4];
#pragma unroll
        for (int nt = 0; nt < 4; nt++)
            b[nt] = *(const short8*)(wb + nt * 16 * K + kk * 32);
#pragma unroll
        for (int mt = 0; mt < 4; mt++)
            a[mt] = *(const short8*)(As + (am + mt * 16) * KP + kk * 32 + aq);
#pragma unroll
        for (int mt = 0; mt < 4; mt++)
#pragma unroll
            for (int nt = 0; nt < 4; nt++)
                acc[mt][nt] = __builtin_amdgcn_mfma_f32_16x16x32_bf16(
                    a[mt], b[nt], acc[mt][nt], 0, 0, 0);
    }

    // ---- epilogue ----
    // C/D layout: col = lane&15 (within 16-tile), row = (lane>>4)*4 + reg
    if (!OUT_BF16) {
        float bv[4] = {0.f, 0.f, 0.f, 0.f};
        if (BIAS) {
#pragma unroll
            for (int nt = 0; nt < 4; nt++) bv[nt] = bias[wn + nt * 16 + (lane & 15)];
        }
#pragma unroll
        for (int mt = 0; mt < 4; mt++) {
#pragma unroll
            for (int reg = 0; reg < 4; reg++) {
                int row = row0 + wm + mt * 16 + (lane >> 4) * 4 + reg;
                if (row >= M) continue;
#pragma unroll
                for (int nt = 0; nt < 4; nt++)
                    Cf[(size_t)row * 128 + wn + nt * 16 + (lane & 15)] =
                        acc[mt][nt][reg] + bv[nt];
            }
        }
    } else {
#pragma unroll
        for (int half = 0; half < 2; half++) {
            __syncthreads();   // As reads done / previous pack done
            if ((w & 1) == half) {
#pragma unroll
                for (int mt = 0; mt < 4; mt++)
#pragma unroll
                    for (int reg = 0; reg < 4; reg++) {
                        int lr = mt * 16 + (lane >> 4) * 4 + reg;   // 0..63
#pragma unroll
                        for (int nt = 0; nt < 4; nt++)
                            Cs[lr * 130 + wn + nt * 16 + (lane & 15)] = acc[mt][nt][reg];
                    }
            }
            __syncthreads();
#pragma unroll
            for (int i = 0; i < 4; i++) {
                int u4 = t + 256 * i;       // 0..1023
                int r  = u4 >> 4;           // 0..63
                int cu = (u4 & 15) * 4;     // uint col
                int grow = row0 + half * 64 + r;
                if (grow < M) {
                    const float* cp = Cs + r * 130 + cu * 2;
                    float2 p0 = *(const float2*)(cp + 0);
                    float2 p1 = *(const float2*)(cp + 2);
                    float2 p2 = *(const float2*)(cp + 4);
                    float2 p3 = *(const float2*)(cp + 6);
                    uint4 o;
                    o.x = f2bf(p0.x) | (f2bf(p0.y) << 16);
                    o.y = f2bf(p1.x) | (f2bf(p1.y) << 16);
                    o.z = f2bf(p2.x) | (f2bf(p2.y) << 16);
                    o.w = f2bf(p3.x) | (f2bf(p3.y) << 16);
                    *(uint4*)(Cb + (size_t)grow * 64 + cu) = o;
                }
            }
        }
    }
}

// ---------------------------------------------------------------------------
// Per-(node,head) attention logits from bf16 hp: es/ed [N,8]
// ---------------------------------------------------------------------------
__global__ __launch_bounds__(256) void att_scores(const unsigned int* __restrict__ hp,
                                                  const float* __restrict__ asrc,
                                                  const float* __restrict__ adst,
                                                  float* __restrict__ es,
                                                  float* __restrict__ ed) {
    int i = blockIdx.x * 256 + threadIdx.x;  // n*8 + head
    if (i >= Nn * 8) return;
    int hh = i & 7;
    const uint4* p = (const uint4*)(hp + (size_t)(i >> 3) * 64 + hh * 8);
    uint4 q0 = p[0], q1 = p[1];
    unsigned int qq[8] = {q0.x, q0.y, q0.z, q0.w, q1.x, q1.y, q1.z, q1.w};
    const float* av = asrc + hh * 16;
    const float* dv = adst + hh * 16;
    float s1 = 0.f, s2 = 0.f;
#pragma unroll
    for (int q = 0; q < 8; q++) {
        float x0 = bf_lo(qq[q]), x1 = bf_hi(qq[q]);
        s1 += x0 * av[2 * q] + x1 * av[2 * q + 1];
        s2 += x0 * dv[2 * q] + x1 * dv[2 * q + 1];
    }
    es[i] = s1;
    ed[i] = s2;
}

// ---------------------------------------------------------------------------
// GAT aggregation, single-pass: one wave per destination node, bf16 gather.
// ---------------------------------------------------------------------------
template <bool AFF>
__global__ __launch_bounds__(256) void gat_attn(const unsigned int* __restrict__ hp,
                                                const float* hin,
                                                const int* __restrict__ batch,
                                                const float* __restrict__ Ab,
                                                const float* __restrict__ Bb,
                                                const float* __restrict__ es,
                                                const float* __restrict__ ed,
                                                const int* __restrict__ rowptr,
                                                const int* __restrict__ col,
                                                const float* __restrict__ gbias,
                                                float* out) {
    int w    = threadIdx.x >> 6;
    int lane = threadIdx.x & 63;
    int n    = blockIdx.x * 4 + w;
    int start = rowptr[n], end = rowptr[n + 1];

    int slot = lane >> 3;   // edge slot within a group of 8
    int ah   = lane & 7;    // head this lane computes weights for
    int ch   = lane >> 3;   // head of channel pair {2*lane, 2*lane+1}

    float edh = ed[(size_t)n * 8 + ah];

    float2 acc = make_float2(0.f, 0.f);
    float dacc = 0.f;

    int e0 = start;
    for (; e0 + 8 <= end; e0 += 8) {
        int src_l = col[e0 + slot];
        float wgt = __expf(lrelu(es[(size_t)src_l * 8 + ah] + edh));
        dacc += wgt;
#pragma unroll
        for (int j = 0; j < 8; j++) {
            int   src_j = __shfl(src_l, j * 8);
            float wj    = __shfl(wgt,   j * 8 + ch);
            unsigned int hv = hp[(size_t)src_j * 64 + lane];
            acc.x += wj * bf_lo(hv);
            acc.y += wj * bf_hi(hv);
        }
    }
    if (e0 < end) {
        int rem = end - e0;                      // 1..7, wave-uniform
        int eb  = e0 + slot;
        int ec  = (slot < rem) ? eb : (end - 1);
        int src_l = col[ec];
        float wgt = (slot < rem) ? __expf(lrelu(es[(size_t)src_l * 8 + ah] + edh)) : 0.f;
        dacc += wgt;
        for (int j = 0; j < rem; j++) {
            int   src_j = __shfl(src_l, j * 8);
            float wj    = __shfl(wgt,   j * 8 + ch);
            unsigned int hv = hp[(size_t)src_j * 64 + lane];
            acc.x += wj * bf_lo(hv);
            acc.y += wj * bf_hi(hv);
        }
    }

    dacc += __shfl_xor(dacc, 8);
    dacc += __shfl_xor(dacc, 16);
    dacc += __shfl_xor(dacc, 32);
    float inv  = 1.0f / (dacc + 1e-16f);
    float winv = __shfl(inv, ch);

    size_t idx = (size_t)n * 128 + 2 * lane;
    float2 xv = *(const float2*)(hin + idx);
    float2 res;
    if (AFF) {
        int g = batch[n];
        float2 Av = *(const float2*)(Ab + g * 128 + 2 * lane);
        float2 Bv = *(const float2*)(Bb + g * 128 + 2 * lane);
        res.x = xv.x * Av.x + Bv.x;
        res.y = xv.y * Av.y + Bv.y;
    } else {
        res = xv;
    }
    float2 o;
    o.x = acc.x * winv + gbias[2 * lane]     + res.x;
    o.y = acc.y * winv + gbias[2 * lane + 1] + res.y;
    *(float2*)(out + idx) = o;
}

// ---------------------------------------------------------------------------
// GraphNorm stats: per (g,c) sum and sumsq; batch is sorted so use run flush.
// ---------------------------------------------------------------------------
#define SCHUNK 64
__global__ __launch_bounds__(128) void gn_stats(const float* __restrict__ x,
                                                const int* __restrict__ batch,
                                                float* __restrict__ sumx,
                                                float* __restrict__ sumxx,
                                                float* __restrict__ cnt) {
    int c  = threadIdx.x;
    int n0 = blockIdx.x * SCHUNK;
    int n1 = n0 + SCHUNK;
    if (n1 > Nn) n1 = Nn;
    if (n0 >= Nn) return;
    int curG = batch[n0];
    float sx = 0.f, sxx = 0.f;
    int run = 0;
    for (int n = n0; n < n1; n++) {
        int g = batch[n];
        if (g != curG) {
            atomicAdd(&sumx[curG * 128 + c], sx);
            atomicAdd(&sumxx[curG * 128 + c], sxx);
            if (c == 0) atomicAdd(&cnt[curG], (float)run);
            sx = 0.f; sxx = 0.f; run = 0; curG = g;
        }
        float v = x[(size_t)n * 128 + c];
        sx += v; sxx += v * v; run++;
    }
    atomicAdd(&sumx[curG * 128 + c], sx);
    atomicAdd(&sumxx[curG * 128 + c], sxx);
    if (c == 0) atomicAdd(&cnt[curG], (float)run);
}

__global__ void gn_final(const float* __restrict__ sumx, const float* __restrict__ sumxx,
                         const float* __restrict__ cnt, const float* __restrict__ w,
                         const float* __restrict__ b, const float* __restrict__ s,
                         float* __restrict__ Ab, float* __restrict__ Bb) {
    int i = blockIdx.x * blockDim.x + threadIdx.x;
    if (i >= Gg * 128) return;
    int g = i >> 7, c = i & 127;
    float cn  = cnt[g];
    float m   = sumx[i] / cn;
    float msq = sumxx[i] / cn;
    float sc  = s[c];
    float varo = msq - (2.f * sc - sc * sc) * m * m;
    float inv  = rsqrtf(varo + EPS_GN);
    float Ai   = inv * w[c];
    Ab[i] = Ai;
    Bb[i] = b[c] - sc * m * Ai;
    (void)g;
}

__global__ __launch_bounds__(256) void gn_apply(const float* __restrict__ x,
                                                const int* __restrict__ batch,
                                                const float* __restrict__ Ab,
                                                const float* __restrict__ Bb,
                                                float* __restrict__ out) {
    int idx = blockIdx.x * 256 + threadIdx.x;
    int n = idx >> 5;
    if (n >= Nn) return;
    int c4 = (idx & 31) << 2;
    int g = batch[n];
    float4 xv = *(const float4*)(x + (size_t)n * 128 + c4);
    float4 Av = *(const float4*)(Ab + g * 128 + c4);
    float4 Bv = *(const float4*)(Bb + g * 128 + c4);
    float4 o;
    o.x = xv.x * Av.x + Bv.x;
    o.y = xv.y * Av.y + Bv.y;
    o.z = xv.z * Av.z + Bv.z;
    o.w = xv.w * Av.w + Bv.w;
    *(float4*)(out + (size_t)n * 128 + c4) = o;
}

// ---------------------------------------------------------------------------
// Launch
// ---------------------------------------------------------------------------
extern "C" void kernel_launch(void* const* d_in, const int* in_sizes, int n_in,
                              void* d_out, int out_size, void* d_ws, size_t ws_size,
                              hipStream_t stream) {
    const float* x      = (const float*)d_in[0];
    const int*   eidx   = (const int*)d_in[1];
    const int*   batch  = (const int*)d_in[2];
    const float* in_W   = (const float*)d_in[3];
    const float* in_b   = (const float*)d_in[4];
    const float* Wg     = (const float*)d_in[5];
    const float* attS   = (const float*)d_in[6];
    const float* attD   = (const float*)d_in[7];
    const float* gat_b  = (const float*)d_in[8];
    const float* gn_w   = (const float*)d_in[9];
    const float* gn_b   = (const float*)d_in[10];
    const float* gn_s   = (const float*)d_in[11];

    const int* esrc = eidx;
    const int* edst = eidx + Ee;

    char* p = (char*)d_ws;
    auto carve = [&](size_t bytes) {
        void* r = (void*)p;
        p += (bytes + 255) & ~(size_t)255;
        return r;
    };
    float* h0   = (float*)carve((size_t)Nn * 128 * 4);
    unsigned int* hp = (unsigned int*)carve((size_t)Nn * 64 * 4);
    float* h2   = (float*)carve((size_t)Nn * 128 * 4);
    float* es   = (float*)carve((size_t)Nn * 8 * 4);
    float* ed   = (float*)carve((size_t)Nn * 8 * 4);
    float* sumx = (float*)carve((size_t)(Gg * 128 * 2 + 16) * 4);
    float* sumxx = sumx + Gg * 128;
    float* cntf  = sumx + Gg * 128 * 2;
    float* Abuf = (float*)carve((size_t)Gg * 128 * 4);
    float* Bbuf = (float*)carve((size_t)Gg * 128 * 4);
    int* rowptr = (int*)carve((size_t)(Nn + 1) * 4);
    int* deg    = (int*)carve((size_t)Nn * 4);
    int* cur    = (int*)carve((size_t)Nn * 4);
    int* col    = (int*)carve((size_t)ETOT * 4);
    int* bsums  = (int*)carve(64 * 4);
    short* Wt0  = (short*)carve((size_t)128 * 64 * 2);
    short* Wtl  = (short*)carve((size_t)4 * 128 * 128 * 2);

    // ---- weight prep + CSR build ----
    prep_w<<<288, 256, 0, stream>>>(in_W, Wg, Wt0, Wtl);
    hipMemsetAsync(deg, 0, (size_t)Nn * 4, stream);
    count_deg<<<768, 256, 0, stream>>>(edst, deg);
    scan1<<<(Nn + 1023) / 1024, 1024, 0, stream>>>(deg, rowptr, bsums);
    scan2<<<1, 64, 0, stream>>>(bsums, (Nn + 1023) / 1024);
    scan3<<<(Nn + 255) / 256, 256, 0, stream>>>(rowptr, bsums);
    hipMemcpyAsync(cur, rowptr, (size_t)Nn * 4, hipMemcpyDeviceToDevice, stream);
    scatter_edges<<<768, 256, 0, stream>>>(esrc, edst, cur, col);

    const int gemm_grid = (Nn + 127) / 128;  // 391

    // ---- input projection: fp32 out + bias ----
    gemm_mfma<64, false, false, true><<<gemm_grid, 256, 0, stream>>>(
        x, nullptr, nullptr, nullptr, Wt0, in_b, h0, nullptr, Nn);

    // ---- layers ----
    for (int l = 0; l < 4; l++) {
        const short* Wl = Wtl + (size_t)l * 128 * 128;
        if (l == 0) {
            gemm_mfma<128, false, true, false><<<gemm_grid, 256, 0, stream>>>(
                h0, nullptr, nullptr, nullptr, Wl, nullptr, nullptr, hp, Nn);
        } else {
            gemm_mfma<128, true, true, false><<<gemm_grid, 256, 0, stream>>>(
                h2, batch, Abuf, Bbuf, Wl, nullptr, nullptr, hp, Nn);
        }
        att_scores<<<(Nn * 8 + 255) / 256, 256, 0, stream>>>(hp, attS + l * 128,
                                                             attD + l * 128, es, ed);
        if (l == 0) {
            gat_attn<false><<<Nn / 4, 256, 0, stream>>>(hp, h0, nullptr, nullptr, nullptr,
                                                        es, ed, rowptr, col,
                                                        gat_b + l * 128, h2);
        } else {
            gat_attn<true><<<Nn / 4, 256, 0, stream>>>(hp, h2, batch, Abuf, Bbuf,
                                                       es, ed, rowptr, col,
                                                       gat_b + l * 128, h2);
        }
        hipMemsetAsync(sumx, 0, (size_t)(Gg * 128 * 2 + 16) * 4, stream);
        gn_stats<<<(Nn + SCHUNK - 1) / SCHUNK, 128, 0, stream>>>(h2, batch, sumx, sumxx, cntf);
        gn_final<<<8, 256, 0, stream>>>(sumx, sumxx, cntf, gn_w + l * 128,
                                        gn_b + l * 128, gn_s + l * 128, Abuf, Bbuf);
    }
    gn_apply<<<(Nn * 32 + 255) / 256, 256, 0, stream>>>(h2, batch, Abuf, Bbuf,
                                                        (float*)d_out);
    (void)in_sizes; (void)n_in; (void)out_size; (void)ws_size;
}

// Round 5
// 575.884 us; speedup vs baseline: 1.7582x; 1.0390x over previous
//
#include <hip/hip_runtime.h>
#include <cstdint>
#include <cstddef>

#define Nn   50000
#define Ee   800000
#define ETOT 850000   // edges + self loops
#define HID  128
#define Gg   16
#define RSZ  6250     // Nn/8 : dst-range size per XCD team
#define NEG_SLOPE 0.2f
#define EPS_GN 1e-5f

typedef __attribute__((ext_vector_type(8))) short short8;
typedef __attribute__((ext_vector_type(4))) float f32x4;

static __device__ __forceinline__ float lrelu(float v) { return v > 0.f ? v : NEG_SLOPE * v; }

// round-to-nearest-even fp32 -> bf16 (low 16 bits of uint)
static __device__ __forceinline__ unsigned int f2bf(float x) {
    unsigned int u = __float_as_uint(x);
    return (u + 0x7fffu + ((u >> 16) & 1u)) >> 16;
}
static __device__ __forceinline__ float bf_lo(unsigned int u) { return __uint_as_float(u << 16); }
static __device__ __forceinline__ float bf_hi(unsigned int u) { return __uint_as_float(u & 0xffff0000u); }

// ---------------------------------------------------------------------------
// Weight prep: bf16 transpose of in_W [64][128]->Wt0[128][64] and
// Wg[4][128][128]->Wtl[4][128][128] ([n][k] layout)
// ---------------------------------------------------------------------------
__global__ void prep_w(const float* __restrict__ in_W, const float* __restrict__ Wg,
                       short* __restrict__ Wt0, short* __restrict__ Wtl) {
    int i = blockIdx.x * 256 + threadIdx.x;
    if (i < 8192) {                       // in-proj: n = i>>6, k = i&63
        int n = i >> 6, k = i & 63;
        Wt0[i] = (short)f2bf(in_W[k * 128 + n]);
    } else if (i < 73728) {
        int j = i - 8192;                 // j = l*16384 + n*128 + k
        int l = j >> 14;
        int rkn = j & 16383;
        int n = rkn >> 7, k = rkn & 127;
        Wtl[j] = (short)f2bf(Wg[l * 16384 + k * 128 + n]);
    }
}

// ---------------------------------------------------------------------------
// CSR build — XCD-partitioned: block b serves dst range (b&7); each team of
// (gridDim/8) blocks scans all edges, filters by range. All writes to
// deg/cur/col lines stay XCD-local -> no cross-XCD partial-line writebacks.
// ---------------------------------------------------------------------------
__global__ void count_deg(const int* __restrict__ edst, int* __restrict__ deg) {
    int r  = blockIdx.x & 7;
    int cb = blockIdx.x >> 3;
    int nb = gridDim.x >> 3;
    int lo = r * RSZ, hi = lo + RSZ;
    for (int i = cb * 256 + threadIdx.x; i < ETOT; i += nb * 256) {
        int dst = (i < Ee) ? edst[i] : (i - Ee);
        if (dst >= lo && dst < hi) atomicAdd(&deg[dst], 1);
    }
}

__global__ void scatter_edges(const int* __restrict__ esrc, const int* __restrict__ edst,
                              int* __restrict__ cur, int* __restrict__ col) {
    int r  = blockIdx.x & 7;
    int cb = blockIdx.x >> 3;
    int nb = gridDim.x >> 3;
    int lo = r * RSZ, hi = lo + RSZ;
    for (int i = cb * 256 + threadIdx.x; i < ETOT; i += nb * 256) {
        int dst = (i < Ee) ? edst[i] : (i - Ee);
        if (dst >= lo && dst < hi) {
            int src = (i < Ee) ? esrc[i] : dst;
            int pos = atomicAdd(&cur[dst], 1);
            col[pos] = src;
        }
    }
}

__global__ __launch_bounds__(1024) void scan1(const int* __restrict__ deg,
                                              int* __restrict__ rowptr,
                                              int* __restrict__ bsums) {
    __shared__ int sm[1024];
    int tid = threadIdx.x;
    int i = blockIdx.x * 1024 + tid;
    sm[tid] = (i < Nn) ? deg[i] : 0;
    __syncthreads();
    for (int off = 1; off < 1024; off <<= 1) {
        int t = 0;
        if (tid >= off) t = sm[tid - off];
        __syncthreads();
        sm[tid] += t;
        __syncthreads();
    }
    if (i < Nn) rowptr[i + 1] = sm[tid];
    if (tid == 1023) bsums[blockIdx.x] = sm[1023];
}

__global__ void scan2(int* __restrict__ bsums, int nb) {
    if (threadIdx.x == 0 && blockIdx.x == 0) {
        int run = 0;
        for (int b = 0; b < nb; b++) { int t = bsums[b]; bsums[b] = run; run += t; }
    }
}

__global__ void scan3(int* __restrict__ rowptr, const int* __restrict__ bsums) {
    int i = blockIdx.x * 256 + threadIdx.x;
    if (i == 0) rowptr[0] = 0;
    if (i < Nn) rowptr[i + 1] += bsums[i >> 10];
}

// ---------------------------------------------------------------------------
// MFMA bf16 GEMM: C[M,128] = affine?(A fp32 -> bf16)[M,K] @ W[K,128]
// Block 128x128, 4 waves (2x2 of 64x64), 16x16x32 bf16 MFMA.
// OUT_BF16: two-pass LDS repack -> packed bf16x2; SCORES: fused es/ed
// (attention logits) computed during the repack read-out.
// ---------------------------------------------------------------------------
template <int K, bool AFFINE, bool OUT_BF16, bool BIAS, bool SCORES>
__global__ __launch_bounds__(256) void gemm_mfma(const float* __restrict__ Ag,
                                                 const int* __restrict__ batch,
                                                 const float* __restrict__ Ab,
                                                 const float* __restrict__ Bb,
                                                 const short* __restrict__ Wt,
                                                 const float* __restrict__ bias,
                                                 const float* __restrict__ asrc,
                                                 const float* __restrict__ adst,
                                                 float* __restrict__ es,
                                                 float* __restrict__ ed,
                                                 float* __restrict__ Cf,
                                                 unsigned int* __restrict__ Cb,
                                                 int M) {
    constexpr int KP = K + 8;                    // padded shorts per A row
    constexpr int ABYTES = 128 * KP * 2;
    constexpr int CBYTES = OUT_BF16 ? 64 * 130 * 4 : 0;
    constexpr int SBYTES = ABYTES > CBYTES ? ABYTES : CBYTES;
    __shared__ __align__(16) char smem[SBYTES];
    short* As = (short*)smem;
    float* Cs = (float*)smem;   // overlays As (used only after all MFMA reads)

    int t    = threadIdx.x;
    int lane = t & 63;
    int w    = t >> 6;
    int wm   = (w & 1) * 64;
    int wn   = (w >> 1) * 64;
    int row0 = blockIdx.x * 128;

    // ---- stage A: fp32 -> bf16 LDS ----
    constexpr int F4R = K / 4;                   // float4 per row
    constexpr int ITERS = 128 * F4R / 256;
#pragma unroll
    for (int i = 0; i < ITERS; i++) {
        int f4 = t + 256 * i;
        int r  = f4 / F4R;
        int c4 = f4 % F4R;
        float4 v = make_float4(0.f, 0.f, 0.f, 0.f);
        int gr = row0 + r;
        if (gr < M) {
            v = *(const float4*)(Ag + (size_t)gr * K + c4 * 4);
            if (AFFINE) {
                int g = batch[gr];
                float4 Av = *(const float4*)(Ab + g * 128 + c4 * 4);
                float4 Bv = *(const float4*)(Bb + g * 128 + c4 * 4);
                v.x = v.x * Av.x + Bv.x;
                v.y = v.y * Av.y + Bv.y;
                v.z = v.z * Av.z + Bv.z;
                v.w = v.w * Av.w + Bv.w;
            }
        }
        uint2 pk;
        pk.x = f2bf(v.x) | (f2bf(v.y) << 16);
        pk.y = f2bf(v.z) | (f2bf(v.w) << 16);
        *(uint2*)(As + r * KP + c4 * 4) = pk;
    }
    __syncthreads();

    // ---- MFMA main loop ----
    f32x4 acc[4][4] = {};
    int am = wm + (lane & 15);
    int aq = (lane >> 4) * 8;
    const short* wb = Wt + (size_t)(wn + (lane & 15)) * K + aq;
#pragma unroll
    for (int kk = 0; kk < K / 32; kk++) {
        short8 a[4], b[4];
#pragma unroll
        for (int nt = 0; nt < 4; nt++)
            b[nt] = *(const short8*)(wb + nt * 16 * K + kk * 32);
#pragma unroll
        for (int mt = 0; mt < 4; mt++)
            a[mt] = *(const short8*)(As + (am + mt * 16) * KP + kk * 32 + aq);
#pragma unroll
        for (int mt = 0; mt < 4; mt++)
#pragma unroll
            for (int nt = 0; nt < 4; nt++)
                acc[mt][nt] = __builtin_amdgcn_mfma_f32_16x16x32_bf16(
                    a[mt], b[nt], acc[mt][nt], 0, 0, 0);
    }

    // ---- epilogue ----
    // C/D layout: col = lane&15 (within 16-tile), row = (lane>>4)*4 + reg
    if (!OUT_BF16) {
        float bv[4] = {0.f, 0.f, 0.f, 0.f};
        if (BIAS) {
#pragma unroll
            for (int nt = 0; nt < 4; nt++) bv[nt] = bias[wn + nt * 16 + (lane & 15)];
        }
#pragma unroll
        for (int mt = 0; mt < 4; mt++) {
#pragma unroll
            for (int reg = 0; reg < 4; reg++) {
                int row = row0 + wm + mt * 16 + (lane >> 4) * 4 + reg;
                if (row >= M) continue;
#pragma unroll
                for (int nt = 0; nt < 4; nt++)
                    Cf[(size_t)row * 128 + wn + nt * 16 + (lane & 15)] =
                        acc[mt][nt][reg] + bv[nt];
            }
        }
    } else {
        // per-thread attention vectors: thread covers channels q*8 .. q*8+7
        float avv[8], dvv[8];
        if (SCORES) {
            int q = t & 15;
#pragma unroll
            for (int k = 0; k < 8; k++) {
                avv[k] = asrc[q * 8 + k];
                dvv[k] = adst[q * 8 + k];
            }
        }
#pragma unroll
        for (int half = 0; half < 2; half++) {
            __syncthreads();   // As reads done / previous pack done
            if ((w & 1) == half) {
#pragma unroll
                for (int mt = 0; mt < 4; mt++)
#pragma unroll
                    for (int reg = 0; reg < 4; reg++) {
                        int lr = mt * 16 + (lane >> 4) * 4 + reg;   // 0..63
#pragma unroll
                        for (int nt = 0; nt < 4; nt++)
                            Cs[lr * 130 + wn + nt * 16 + (lane & 15)] = acc[mt][nt][reg];
                    }
            }
            __syncthreads();
#pragma unroll
            for (int i = 0; i < 4; i++) {
                int u4 = t + 256 * i;       // 0..1023
                int r  = u4 >> 4;           // 0..63
                int cu = (u4 & 15) * 4;     // uint col
                int grow = row0 + half * 64 + r;
                if (grow < M) {
                    const float* cp = Cs + r * 130 + cu * 2;
                    float2 p0 = *(const float2*)(cp + 0);
                    float2 p1 = *(const float2*)(cp + 2);
                    float2 p2 = *(const float2*)(cp + 4);
                    float2 p3 = *(const float2*)(cp + 6);
                    uint4 o;
                    o.x = f2bf(p0.x) | (f2bf(p0.y) << 16);
                    o.y = f2bf(p1.x) | (f2bf(p1.y) << 16);
                    o.z = f2bf(p2.x) | (f2bf(p2.y) << 16);
                    o.w = f2bf(p3.x) | (f2bf(p3.y) << 16);
                    *(uint4*)(Cb + (size_t)grow * 64 + cu) = o;
                    if (SCORES) {
                        float s1 = p0.x * avv[0] + p0.y * avv[1] + p1.x * avv[2] +
                                   p1.y * avv[3] + p2.x * avv[4] + p2.y * avv[5] +
                                   p3.x * avv[6] + p3.y * avv[7];
                        float s2 = p0.x * dvv[0] + p0.y * dvv[1] + p1.x * dvv[2] +
                                   p1.y * dvv[3] + p2.x * dvv[4] + p2.y * dvv[5] +
                                   p3.x * dvv[6] + p3.y * dvv[7];
                        s1 += __shfl_xor(s1, 1);
                        s2 += __shfl_xor(s2, 1);
                        if ((t & 1) == 0) {
                            int hh = (t & 15) >> 1;
                            es[(size_t)grow * 8 + hh] = s1;
                            ed[(size_t)grow * 8 + hh] = s2;
                        }
                    }
                }
            }
        }
    }
}

// ---------------------------------------------------------------------------
// GAT aggregation v3: one wave per destination node, half-wave per edge.
// Weight phase: lane (slot=lane>>3, head=lane&7) computes exp weight for
// edge-slot in a group of 8 (unified clamp for remainders).
// Accumulate phase: lane (half=lane>>5, sl=lane&31) holds channels 4*sl..+3
// (uint2 bf16x4 gather); wave does 2 edges per inner step (one per half).
// Cross-half combine + slot-reduce denominator via shuffles.
// ---------------------------------------------------------------------------
template <bool AFF>
__global__ __launch_bounds__(256) void gat_attn(const unsigned int* __restrict__ hp,
                                                const float* hin,
                                                const int* __restrict__ batch,
                                                const float* __restrict__ Ab,
                                                const float* __restrict__ Bb,
                                                const float* __restrict__ es,
                                                const float* __restrict__ ed,
                                                const int* __restrict__ rowptr,
                                                const int* __restrict__ col,
                                                const float* __restrict__ gbias,
                                                float* out) {
    int w    = threadIdx.x >> 6;
    int lane = threadIdx.x & 63;
    int n    = blockIdx.x * 4 + w;
    int start = rowptr[n], end = rowptr[n + 1];

    int slot = lane >> 3;   // edge slot (weight phase)
    int ah   = lane & 7;    // head (weight phase)
    int half = lane >> 5;   // edge parity (accumulate phase)
    int sl   = lane & 31;   // channel group: channels 4*sl .. 4*sl+3
    int hd   = sl >> 2;     // head of this lane's channels

    float edh = ed[(size_t)n * 8 + ah];
    const unsigned int* hpl = hp + sl * 2;

    float a0 = 0.f, a1 = 0.f, a2 = 0.f, a3 = 0.f;
    float dacc = 0.f;

    for (int e0 = start; e0 < end; e0 += 8) {
        int ee = e0 + slot;
        bool valid = ee < end;
        int ec = valid ? ee : (end - 1);          // rows non-empty (self-loop)
        int src_l = col[ec];
        float wgt = valid ? __expf(lrelu(es[(size_t)src_l * 8 + ah] + edh)) : 0.f;
        dacc += wgt;
#pragma unroll
        for (int jj = 0; jj < 4; jj++) {
            int e = jj * 2 + half;
            int   src_j = __shfl(src_l, e * 8);
            float wj    = __shfl(wgt,   e * 8 + hd);
            uint2 hv = *(const uint2*)(hpl + (size_t)src_j * 64);
            a0 += wj * bf_lo(hv.x);
            a1 += wj * bf_hi(hv.x);
            a2 += wj * bf_lo(hv.y);
            a3 += wj * bf_hi(hv.y);
        }
    }

    // combine the two halves (each saw edges of one parity)
    a0 += __shfl_xor(a0, 32);
    a1 += __shfl_xor(a1, 32);
    a2 += __shfl_xor(a2, 32);
    a3 += __shfl_xor(a3, 32);

    // denominator: sum over the 8 slots sharing head `ah`
    dacc += __shfl_xor(dacc, 8);
    dacc += __shfl_xor(dacc, 16);
    dacc += __shfl_xor(dacc, 32);
    float inv  = 1.0f / (dacc + 1e-16f);
    float winv = __shfl(inv, hd);       // lane hd has ah == hd

    if (half == 0) {
        size_t idx = (size_t)n * 128 + sl * 4;
        float4 xv = *(const float4*)(hin + idx);
        float4 res;
        if (AFF) {
            int g = batch[n];
            float4 Av = *(const float4*)(Ab + g * 128 + sl * 4);
            float4 Bv = *(const float4*)(Bb + g * 128 + sl * 4);
            res.x = xv.x * Av.x + Bv.x;
            res.y = xv.y * Av.y + Bv.y;
            res.z = xv.z * Av.z + Bv.z;
            res.w = xv.w * Av.w + Bv.w;
        } else {
            res = xv;
        }
        float4 bv = *(const float4*)(gbias + sl * 4);
        float4 o;
        o.x = a0 * winv + bv.x + res.x;
        o.y = a1 * winv + bv.y + res.y;
        o.z = a2 * winv + bv.z + res.z;
        o.w = a3 * winv + bv.w + res.w;
        *(float4*)(out + idx) = o;
    }
}

// ---------------------------------------------------------------------------
// GraphNorm stats: per (g,c) sum and sumsq; batch is sorted so use run flush.
// ---------------------------------------------------------------------------
#define SCHUNK 64
__global__ __launch_bounds__(128) void gn_stats(const float* __restrict__ x,
                                                const int* __restrict__ batch,
                                                float* __restrict__ sumx,
                                                float* __restrict__ sumxx,
                                                float* __restrict__ cnt) {
    int c  = threadIdx.x;
    int n0 = blockIdx.x * SCHUNK;
    int n1 = n0 + SCHUNK;
    if (n1 > Nn) n1 = Nn;
    if (n0 >= Nn) return;
    int curG = batch[n0];
    float sx = 0.f, sxx = 0.f;
    int run = 0;
    for (int n = n0; n < n1; n++) {
        int g = batch[n];
        if (g != curG) {
            atomicAdd(&sumx[curG * 128 + c], sx);
            atomicAdd(&sumxx[curG * 128 + c], sxx);
            if (c == 0) atomicAdd(&cnt[curG], (float)run);
            sx = 0.f; sxx = 0.f; run = 0; curG = g;
        }
        float v = x[(size_t)n * 128 + c];
        sx += v; sxx += v * v; run++;
    }
    atomicAdd(&sumx[curG * 128 + c], sx);
    atomicAdd(&sumxx[curG * 128 + c], sxx);
    if (c == 0) atomicAdd(&cnt[curG], (float)run);
}

__global__ void gn_final(const float* __restrict__ sumx, const float* __restrict__ sumxx,
                         const float* __restrict__ cnt, const float* __restrict__ w,
                         const float* __restrict__ b, const float* __restrict__ s,
                         float* __restrict__ Ab, float* __restrict__ Bb) {
    int i = blockIdx.x * blockDim.x + threadIdx.x;
    if (i >= Gg * 128) return;
    int g = i >> 7, c = i & 127;
    float cn  = cnt[g];
    float m   = sumx[i] / cn;
    float msq = sumxx[i] / cn;
    float sc  = s[c];
    float varo = msq - (2.f * sc - sc * sc) * m * m;
    float inv  = rsqrtf(varo + EPS_GN);
    float Ai   = inv * w[c];
    Ab[i] = Ai;
    Bb[i] = b[c] - sc * m * Ai;
    (void)g;
}

__global__ __launch_bounds__(256) void gn_apply(const float* __restrict__ x,
                                                const int* __restrict__ batch,
                                                const float* __restrict__ Ab,
                                                const float* __restrict__ Bb,
                                                float* __restrict__ out) {
    int idx = blockIdx.x * 256 + threadIdx.x;
    int n = idx >> 5;
    if (n >= Nn) return;
    int c4 = (idx & 31) << 2;
    int g = batch[n];
    float4 xv = *(const float4*)(x + (size_t)n * 128 + c4);
    float4 Av = *(const float4*)(Ab + g * 128 + c4);
    float4 Bv = *(const float4*)(Bb + g * 128 + c4);
    float4 o;
    o.x = xv.x * Av.x + Bv.x;
    o.y = xv.y * Av.y + Bv.y;
    o.z = xv.z * Av.z + Bv.z;
    o.w = xv.w * Av.w + Bv.w;
    *(float4*)(out + (size_t)n * 128 + c4) = o;
}

// ---------------------------------------------------------------------------
// Launch
// ---------------------------------------------------------------------------
extern "C" void kernel_launch(void* const* d_in, const int* in_sizes, int n_in,
                              void* d_out, int out_size, void* d_ws, size_t ws_size,
                              hipStream_t stream) {
    const float* x      = (const float*)d_in[0];
    const int*   eidx   = (const int*)d_in[1];
    const int*   batch  = (const int*)d_in[2];
    const float* in_W   = (const float*)d_in[3];
    const float* in_b   = (const float*)d_in[4];
    const float* Wg     = (const float*)d_in[5];
    const float* attS   = (const float*)d_in[6];
    const float* attD   = (const float*)d_in[7];
    const float* gat_b  = (const float*)d_in[8];
    const float* gn_w   = (const float*)d_in[9];
    const float* gn_b   = (const float*)d_in[10];
    const float* gn_s   = (const float*)d_in[11];

    const int* esrc = eidx;
    const int* edst = eidx + Ee;

    char* p = (char*)d_ws;
    auto carve = [&](size_t bytes) {
        void* r = (void*)p;
        p += (bytes + 255) & ~(size_t)255;
        return r;
    };
    float* h0   = (float*)carve((size_t)Nn * 128 * 4);
    unsigned int* hp = (unsigned int*)carve((size_t)Nn * 64 * 4);
    float* h2   = (float*)carve((size_t)Nn * 128 * 4);
    float* es   = (float*)carve((size_t)Nn * 8 * 4);
    float* ed   = (float*)carve((size_t)Nn * 8 * 4);
    float* sumx = (float*)carve((size_t)(Gg * 128 * 2 + 16) * 4);
    float* sumxx = sumx + Gg * 128;
    float* cntf  = sumx + Gg * 128 * 2;
    float* Abuf = (float*)carve((size_t)Gg * 128 * 4);
    float* Bbuf = (float*)carve((size_t)Gg * 128 * 4);
    int* rowptr = (int*)carve((size_t)(Nn + 1) * 4);
    int* deg    = (int*)carve((size_t)Nn * 4);
    int* cur    = (int*)carve((size_t)Nn * 4);
    int* col    = (int*)carve((size_t)ETOT * 4);
    int* bsums  = (int*)carve(64 * 4);
    short* Wt0  = (short*)carve((size_t)128 * 64 * 2);
    short* Wtl  = (short*)carve((size_t)4 * 128 * 128 * 2);

    // ---- weight prep + CSR build ----
    prep_w<<<288, 256, 0, stream>>>(in_W, Wg, Wt0, Wtl);
    hipMemsetAsync(deg, 0, (size_t)Nn * 4, stream);
    count_deg<<<768, 256, 0, stream>>>(edst, deg);
    scan1<<<(Nn + 1023) / 1024, 1024, 0, stream>>>(deg, rowptr, bsums);
    scan2<<<1, 64, 0, stream>>>(bsums, (Nn + 1023) / 1024);
    scan3<<<(Nn + 255) / 256, 256, 0, stream>>>(rowptr, bsums);
    hipMemcpyAsync(cur, rowptr, (size_t)Nn * 4, hipMemcpyDeviceToDevice, stream);
    scatter_edges<<<768, 256, 0, stream>>>(esrc, edst, cur, col);

    const int gemm_grid = (Nn + 127) / 128;  // 391

    // ---- input projection: fp32 out + bias ----
    gemm_mfma<64, false, false, true, false><<<gemm_grid, 256, 0, stream>>>(
        x, nullptr, nullptr, nullptr, Wt0, in_b, nullptr, nullptr, nullptr, nullptr,
        h0, nullptr, Nn);

    // ---- layers ----
    for (int l = 0; l < 4; l++) {
        const short* Wl = Wtl + (size_t)l * 128 * 128;
        if (l == 0) {
            gemm_mfma<128, false, true, false, true><<<gemm_grid, 256, 0, stream>>>(
                h0, nullptr, nullptr, nullptr, Wl, nullptr,
                attS + l * 128, attD + l * 128, es, ed, nullptr, hp, Nn);
        } else {
            gemm_mfma<128, true, true, false, true><<<gemm_grid, 256, 0, stream>>>(
                h2, batch, Abuf, Bbuf, Wl, nullptr,
                attS + l * 128, attD + l * 128, es, ed, nullptr, hp, Nn);
        }
        if (l == 0) {
            gat_attn<false><<<Nn / 4, 256, 0, stream>>>(hp, h0, nullptr, nullptr, nullptr,
                                                        es, ed, rowptr, col,
                                                        gat_b + l * 128, h2);
        } else {
            gat_attn<true><<<Nn / 4, 256, 0, stream>>>(hp, h2, batch, Abuf, Bbuf,
                                                       es, ed, rowptr, col,
                                                       gat_b + l * 128, h2);
        }
        hipMemsetAsync(sumx, 0, (size_t)(Gg * 128 * 2 + 16) * 4, stream);
        gn_stats<<<(Nn + SCHUNK - 1) / SCHUNK, 128, 0, stream>>>(h2, batch, sumx, sumxx, cntf);
        gn_final<<<8, 256, 0, stream>>>(sumx, sumxx, cntf, gn_w + l * 128,
                                        gn_b + l * 128, gn_s + l * 128, Abuf, Bbuf);
    }
    gn_apply<<<(Nn * 32 + 255) / 256, 256, 0, stream>>>(h2, batch, Abuf, Bbuf,
                                                        (float*)d_out);
    (void)in_sizes; (void)n_in; (void)out_size; (void)ws_size;
}